// Round 9
// baseline (21072.859 us; speedup 1.0000x reference)
//
#include <hip/hip_runtime.h>
#include <hip/hip_bf16.h>

__device__ __forceinline__ float sigmoidf_(float x) {
    return 1.0f / (1.0f + __expf(-x));
}
__device__ __forceinline__ float tanhf_(float x) {
    float e = __expf(2.0f * x);
    return 1.0f - 2.0f / (e + 1.0f);
}

// ---------------------------------------------------------------------------
// h0[node] = GRU step with hprev=0 (gh = bhh). Wih staged in LDS.
// ---------------------------------------------------------------------------
__global__ __launch_bounds__(256) void compute_h0(
    const float* __restrict__ h, const float* __restrict__ Wih,
    const float* __restrict__ bih, const float* __restrict__ bhh,
    float* __restrict__ h0, int n1)
{
    __shared__ float sW[3072];
    __shared__ float sB[192];
    {
        const float4* a4 = (const float4*)Wih;
        float4* sa = (float4*)sW;
#pragma unroll
        for (int c = 0; c < 3; ++c)
            sa[c * 256 + threadIdx.x] = a4[c * 256 + threadIdx.x];
        if (threadIdx.x < 192)
            sB[threadIdx.x] = (threadIdx.x < 96) ? bih[threadIdx.x]
                                                 : bhh[threadIdx.x - 96];
    }
    __syncthreads();

    int node = blockIdx.x * 256 + threadIdx.x;
    if (node >= n1) return;
    float x[32];
    const float4* hx = (const float4*)(h + (size_t)node * 32);
#pragma unroll
    for (int c = 0; c < 8; ++c) {
        float4 v = hx[c];
        x[c*4+0] = v.x; x[c*4+1] = v.y; x[c*4+2] = v.z; x[c*4+3] = v.w;
    }
    float o[32];
#pragma unroll
    for (int j = 0; j < 32; ++j) {
        float ir = sB[j], iz = sB[32 + j], in_ = sB[64 + j];
        const float4* wr = (const float4*)(sW + j * 32);
        const float4* wz = (const float4*)(sW + (32 + j) * 32);
        const float4* wn = (const float4*)(sW + (64 + j) * 32);
#pragma unroll
        for (int c = 0; c < 8; ++c) {
            float4 a = wr[c], b = wz[c], d = wn[c];
            ir  += x[c*4+0]*a.x + x[c*4+1]*a.y + x[c*4+2]*a.z + x[c*4+3]*a.w;
            iz  += x[c*4+0]*b.x + x[c*4+1]*b.y + x[c*4+2]*b.z + x[c*4+3]*b.w;
            in_ += x[c*4+0]*d.x + x[c*4+1]*d.y + x[c*4+2]*d.z + x[c*4+3]*d.w;
        }
        float r = sigmoidf_(ir + sB[96 + j]);
        float z = sigmoidf_(iz + sB[128 + j]);
        float n = tanhf_(in_ + r * sB[160 + j]);
        o[j] = (1.0f - z) * n;
    }
    float4* dst = (float4*)(h0 + (size_t)node * 32);
#pragma unroll
    for (int c = 0; c < 8; ++c)
        dst[c] = make_float4(o[c*4+0], o[c*4+1], o[c*4+2], o[c*4+3]);
}

// ---------------------------------------------------------------------------
// Batched histogram per k-list: col 0 -> cnt0, cols t>=1 -> counts[(t-1)*n1+]
// ---------------------------------------------------------------------------
template <int K>
__global__ __launch_bounds__(256) void hist_all(
    const int* __restrict__ idx, int nI, int* __restrict__ cnt0,
    int* __restrict__ counts, int n1)
{
    int i = blockIdx.x * 256 + threadIdx.x;
    if (i >= nI) return;
    int t = i % K;
    int node = idx[i];
    if (t == 0) atomicAdd(&cnt0[node], 1);
    else        atomicAdd(&counts[(size_t)(t - 1) * n1 + node], 1);
}

// ---------------------------------------------------------------------------
// Scan machinery (3-level)
// ---------------------------------------------------------------------------
__global__ __launch_bounds__(256) void scan_block(
    const int* __restrict__ in, int* __restrict__ incl,
    int* __restrict__ bsums, int n)
{
    __shared__ int s[256];
    int i = blockIdx.x * 256 + threadIdx.x;
    int v = (i < n) ? in[i] : 0;
    s[threadIdx.x] = v;
    __syncthreads();
    for (int d = 1; d < 256; d <<= 1) {
        int tt = (threadIdx.x >= d) ? s[threadIdx.x - d] : 0;
        __syncthreads();
        s[threadIdx.x] += tt;
        __syncthreads();
    }
    if (i < n) incl[i] = s[threadIdx.x];
    if (threadIdx.x == 255) bsums[blockIdx.x] = s[255];
}

__global__ __launch_bounds__(1024) void scan_bsums(int* bsums, int nb)
{
    __shared__ int s[1024];
    int v = (threadIdx.x < nb) ? bsums[threadIdx.x] : 0;
    s[threadIdx.x] = v;
    __syncthreads();
    for (int d = 1; d < 1024; d <<= 1) {
        int tt = (threadIdx.x >= d) ? s[threadIdx.x - d] : 0;
        __syncthreads();
        s[threadIdx.x] += tt;
        __syncthreads();
    }
    if (threadIdx.x < nb) bsums[threadIdx.x] = s[threadIdx.x] - v; // exclusive
}

// offs[i] (in-place over incl0) = global EXCLUSIVE prefix of counts
__global__ __launch_bounds__(256) void finalize_joint(
    int* __restrict__ offs, const int* __restrict__ counts,
    const int* __restrict__ bsums0, const int* __restrict__ incl1,
    const int* __restrict__ bsums1ex, int M)
{
    int i = blockIdx.x * 256 + threadIdx.x;
    if (i >= M) return;
    int b0 = i >> 8, b1 = b0 >> 8;
    offs[i] = offs[i] - counts[i] + (incl1[b0] - bsums0[b0]) + bsums1ex[b1];
}

// ---------------------------------------------------------------------------
// Batched ticket fill for columns t>=1 of a k-list
// ---------------------------------------------------------------------------
template <int K>
__global__ __launch_bounds__(256) void fill_all(
    const int* __restrict__ idx, int nW,   // nW = nE*(K-1)
    int* __restrict__ cursor, int* __restrict__ ent, int n1)
{
    int i = blockIdx.x * 256 + threadIdx.x;
    if (i >= nW) return;
    int e = i / (K - 1), tt = i % (K - 1);
    int node = idx[(size_t)e * K + tt + 1];
    int p = atomicAdd(&cursor[(size_t)tt * n1 + node], 1);
    ent[p] = e;
}

// ---------------------------------------------------------------------------
// One GRU step (t = T >= 1), 2 edges per thread (Te=2 register tile).
// Weights+biases in LDS; each weight float4 read feeds BOTH edges' FMAs
// (0.5 LDS reads per FMA vs 1.0 at Te=1). x,hv for both edges in VGPRs.
// __launch_bounds__(256,2): cap 256 VGPR -> 2 waves/SIMD, no spill.
// ---------------------------------------------------------------------------
template <int K, int T>
__global__ __launch_bounds__(256, 2) void gru_step_h(
    const int* __restrict__ idx, int nE,
    const float* __restrict__ h, const float* __restrict__ h0,
    const float* __restrict__ Wih, const float* __restrict__ bih,
    const float* __restrict__ Whh, const float* __restrict__ bhh,
    float* __restrict__ hstate)
{
    __shared__ float sWih[3072];
    __shared__ float sWhh[3072];
    __shared__ float sB[192];
    {
        const float4* a4 = (const float4*)Wih;
        const float4* b4 = (const float4*)Whh;
        float4* sa = (float4*)sWih;
        float4* sb = (float4*)sWhh;
#pragma unroll
        for (int c = 0; c < 3; ++c) {
            sa[c * 256 + threadIdx.x] = a4[c * 256 + threadIdx.x];
            sb[c * 256 + threadIdx.x] = b4[c * 256 + threadIdx.x];
        }
        if (threadIdx.x < 192)
            sB[threadIdx.x] = (threadIdx.x < 96) ? bih[threadIdx.x]
                                                 : bhh[threadIdx.x - 96];
    }
    __syncthreads();

    int e0 = blockIdx.x * 512 + threadIdx.x;
    if (e0 >= nE) return;
    int e1 = e0 + 256;
    bool v1 = (e1 < nE);
    int e1c = v1 ? e1 : e0;

    float hv0[32], hv1[32];
    if (T == 1) {
        int a0 = idx[(size_t)e0 * K];
        int a1 = idx[(size_t)e1c * K];
        const float4* p0 = (const float4*)(h0 + (size_t)a0 * 32);
        const float4* p1 = (const float4*)(h0 + (size_t)a1 * 32);
#pragma unroll
        for (int c = 0; c < 8; ++c) {
            float4 u = p0[c], w = p1[c];
            hv0[c*4+0]=u.x; hv0[c*4+1]=u.y; hv0[c*4+2]=u.z; hv0[c*4+3]=u.w;
            hv1[c*4+0]=w.x; hv1[c*4+1]=w.y; hv1[c*4+2]=w.z; hv1[c*4+3]=w.w;
        }
    } else {
        const float4* p0 = (const float4*)(hstate + (size_t)e0 * 32);
        const float4* p1 = (const float4*)(hstate + (size_t)e1c * 32);
#pragma unroll
        for (int c = 0; c < 8; ++c) {
            float4 u = p0[c], w = p1[c];
            hv0[c*4+0]=u.x; hv0[c*4+1]=u.y; hv0[c*4+2]=u.z; hv0[c*4+3]=u.w;
            hv1[c*4+0]=w.x; hv1[c*4+1]=w.y; hv1[c*4+2]=w.z; hv1[c*4+3]=w.w;
        }
    }

    float x0[32], x1[32];
    {
        int n0 = idx[(size_t)e0 * K + T];
        int n1_ = idx[(size_t)e1c * K + T];
        const float4* p0 = (const float4*)(h + (size_t)n0 * 32);
        const float4* p1 = (const float4*)(h + (size_t)n1_ * 32);
#pragma unroll
        for (int c = 0; c < 8; ++c) {
            float4 u = p0[c], w = p1[c];
            x0[c*4+0]=u.x; x0[c*4+1]=u.y; x0[c*4+2]=u.z; x0[c*4+3]=u.w;
            x1[c*4+0]=w.x; x1[c*4+1]=w.y; x1[c*4+2]=w.z; x1[c*4+3]=w.w;
        }
    }

    float4* hs0 = (float4*)(hstate + (size_t)e0 * 32);
    float4* hs1 = (float4*)(hstate + (size_t)e1 * 32);

#pragma unroll
    for (int jb = 0; jb < 8; ++jb) {
        float hnb0[4], hnb1[4];
#pragma unroll
        for (int q = 0; q < 4; ++q) {
            const int j = jb * 4 + q;
            float ir0 = sB[j], iz0 = sB[32 + j], in0 = sB[64 + j];
            float hr0 = sB[96 + j], hz0 = sB[128 + j], hn20 = sB[160 + j];
            float ir1 = ir0, iz1 = iz0, in1 = in0;
            float hr1 = hr0, hz1 = hz0, hn21 = hn20;
            const float4* wr4 = (const float4*)(sWih + j * 32);
            const float4* wz4 = (const float4*)(sWih + (32 + j) * 32);
            const float4* wn4 = (const float4*)(sWih + (64 + j) * 32);
            const float4* ur4 = (const float4*)(sWhh + j * 32);
            const float4* uz4 = (const float4*)(sWhh + (32 + j) * 32);
            const float4* un4 = (const float4*)(sWhh + (64 + j) * 32);
#pragma unroll
            for (int c = 0; c < 8; ++c) {
                float4 wa = wr4[c], wb = wz4[c], wc = wn4[c];
                float4 va = ur4[c], vb = uz4[c], vc = un4[c];
                float a0 = x0[c*4+0], a1 = x0[c*4+1], a2 = x0[c*4+2], a3 = x0[c*4+3];
                float b0 = x1[c*4+0], b1 = x1[c*4+1], b2 = x1[c*4+2], b3 = x1[c*4+3];
                float g0 = hv0[c*4+0], g1 = hv0[c*4+1], g2 = hv0[c*4+2], g3 = hv0[c*4+3];
                float k0 = hv1[c*4+0], k1 = hv1[c*4+1], k2 = hv1[c*4+2], k3 = hv1[c*4+3];
                ir0  += a0*wa.x + a1*wa.y + a2*wa.z + a3*wa.w;
                iz0  += a0*wb.x + a1*wb.y + a2*wb.z + a3*wb.w;
                in0  += a0*wc.x + a1*wc.y + a2*wc.z + a3*wc.w;
                hr0  += g0*va.x + g1*va.y + g2*va.z + g3*va.w;
                hz0  += g0*vb.x + g1*vb.y + g2*vb.z + g3*vb.w;
                hn20 += g0*vc.x + g1*vc.y + g2*vc.z + g3*vc.w;
                ir1  += b0*wa.x + b1*wa.y + b2*wa.z + b3*wa.w;
                iz1  += b0*wb.x + b1*wb.y + b2*wb.z + b3*wb.w;
                in1  += b0*wc.x + b1*wc.y + b2*wc.z + b3*wc.w;
                hr1  += k0*va.x + k1*va.y + k2*va.z + k3*va.w;
                hz1  += k0*vb.x + k1*vb.y + k2*vb.z + k3*vb.w;
                hn21 += k0*vc.x + k1*vc.y + k2*vc.z + k3*vc.w;
            }
            {
                float r = sigmoidf_(ir0 + hr0);
                float z = sigmoidf_(iz0 + hz0);
                float n = tanhf_(in0 + r * hn20);
                hnb0[q] = (1.0f - z) * n + z * hv0[j];
            }
            {
                float r = sigmoidf_(ir1 + hr1);
                float z = sigmoidf_(iz1 + hz1);
                float n = tanhf_(in1 + r * hn21);
                hnb1[q] = (1.0f - z) * n + z * hv1[j];
            }
        }
        hs0[jb] = make_float4(hnb0[0], hnb0[1], hnb0[2], hnb0[3]);
        if (v1) hs1[jb] = make_float4(hnb1[0], hnb1[1], hnb1[2], hnb1[3]);
    }
}

// ---------------------------------------------------------------------------
// hkk[node] = cnt0[node] * h0[node]
// ---------------------------------------------------------------------------
__global__ __launch_bounds__(256) void init_hkk(
    const int* __restrict__ cnt0, const float* __restrict__ h0,
    float* __restrict__ hkk, int n1)
{
    int gid = blockIdx.x * 256 + threadIdx.x;
    int node = gid >> 3;
    int sub = gid & 7;
    if (node >= n1) return;
    float c = (float)cnt0[node];
    float4 v = *(const float4*)(h0 + (size_t)node * 32 + sub * 4);
    v.x *= c; v.y *= c; v.z *= c; v.w *= c;
    *(float4*)(hkk + (size_t)node * 32 + sub * 4) = v;
}

// ---------------------------------------------------------------------------
// hkk[node] += sum over entries of hstate rows. 8 threads/node, no atomics.
// ---------------------------------------------------------------------------
__global__ __launch_bounds__(256) void gather_add(
    const int* __restrict__ offs, const int* __restrict__ endp,
    const int* __restrict__ ent,
    const float* __restrict__ hstate, float* __restrict__ hkk, int n1)
{
    int gid = blockIdx.x * 256 + threadIdx.x;
    int node = gid >> 3;
    int sub = gid & 7;
    if (node >= n1) return;
    int beg = offs[node], end = endp[node];
    if (beg == end) return;
    float4 a = make_float4(0.f, 0.f, 0.f, 0.f);
    for (int p = beg; p < end; ++p) {
        int e = ent[p];
        float4 v = *(const float4*)(hstate + (size_t)e * 32 + sub * 4);
        a.x += v.x; a.y += v.y; a.z += v.z; a.w += v.w;
    }
    float* dst = hkk + (size_t)node * 32 + sub * 4;
    float4 cur = *(float4*)dst;
    cur.x += a.x; cur.y += a.y; cur.z += a.z; cur.w += a.w;
    *(float4*)dst = cur;
}

// ---------------------------------------------------------------------------
// acc(=out)[node] = b1 + h[node] @ W1[:,0:32].T   (W1 block 0 staged in LDS)
// ---------------------------------------------------------------------------
__global__ __launch_bounds__(256) void init_acc(
    const float* __restrict__ h, const float* __restrict__ W1,
    const float* __restrict__ b1, float* __restrict__ acc, int n1)
{
    __shared__ float sW[1024];
#pragma unroll
    for (int c = 0; c < 4; ++c) {
        int i = c * 256 + threadIdx.x;
        sW[i] = W1[(i >> 5) * 128 + (i & 31)];
    }
    __syncthreads();

    int node = blockIdx.x * 256 + threadIdx.x;
    if (node >= n1) return;
    float x[32];
    const float4* hx = (const float4*)(h + (size_t)node * 32);
#pragma unroll
    for (int c = 0; c < 8; ++c) {
        float4 v = hx[c];
        x[c*4+0] = v.x; x[c*4+1] = v.y; x[c*4+2] = v.z; x[c*4+3] = v.w;
    }
    float* arow = acc + (size_t)node * 32;
#pragma unroll
    for (int jb = 0; jb < 8; ++jb) {
        float o[4];
#pragma unroll
        for (int q = 0; q < 4; ++q) {
            int j = jb * 4 + q;
            float a = b1[j];
            const float4* w4 = (const float4*)(sW + j * 32);
#pragma unroll
            for (int c = 0; c < 8; ++c) {
                float4 w = w4[c];
                a += x[c*4+0]*w.x + x[c*4+1]*w.y + x[c*4+2]*w.z + x[c*4+3]*w.w;
            }
            o[q] = a;
        }
        *(float4*)(arow + jb * 4) = make_float4(o[0], o[1], o[2], o[3]);
    }
}

// ---------------------------------------------------------------------------
// acc(=out)[node] += hkk[node] @ W1blk.T  (block staged in LDS)
// ---------------------------------------------------------------------------
__global__ __launch_bounds__(256) void fold_w1(
    const float* __restrict__ hkk, const float* __restrict__ W1blk,
    float* __restrict__ acc, int n1)
{
    __shared__ float sW[1024];
#pragma unroll
    for (int c = 0; c < 4; ++c) {
        int i = c * 256 + threadIdx.x;
        sW[i] = W1blk[(i >> 5) * 128 + (i & 31)];
    }
    __syncthreads();

    int node = blockIdx.x * 256 + threadIdx.x;
    if (node >= n1) return;
    float x[32];
    const float4* hx = (const float4*)(hkk + (size_t)node * 32);
#pragma unroll
    for (int c = 0; c < 8; ++c) {
        float4 v = hx[c];
        x[c*4+0] = v.x; x[c*4+1] = v.y; x[c*4+2] = v.z; x[c*4+3] = v.w;
    }
    float* arow = acc + (size_t)node * 32;
#pragma unroll
    for (int jb = 0; jb < 8; ++jb) {
        float4 cur = *(float4*)(arow + jb * 4);
        float o[4] = { cur.x, cur.y, cur.z, cur.w };
#pragma unroll
        for (int q = 0; q < 4; ++q) {
            int j = jb * 4 + q;
            float a = o[q];
            const float4* w4 = (const float4*)(sW + j * 32);
#pragma unroll
            for (int c = 0; c < 8; ++c) {
                float4 w = w4[c];
                a += x[c*4+0]*w.x + x[c*4+1]*w.y + x[c*4+2]*w.z + x[c*4+3]*w.w;
            }
            o[q] = a;
        }
        *(float4*)(arow + jb * 4) = make_float4(o[0], o[1], o[2], o[3]);
    }
}

// ---------------------------------------------------------------------------
// out[node] = tanh(acc[node]) @ W2.T + b2   (in-place; W2 staged in LDS)
// ---------------------------------------------------------------------------
__global__ __launch_bounds__(256) void finish_out(
    float* __restrict__ acc, const float* __restrict__ W2,
    const float* __restrict__ b2, int n1)
{
    __shared__ float sW[1024];
    {
        const float4* w4 = (const float4*)W2;
        float4* s4 = (float4*)sW;
        if (threadIdx.x < 256) s4[threadIdx.x] = w4[threadIdx.x];
    }
    __syncthreads();

    int node = blockIdx.x * 256 + threadIdx.x;
    if (node >= n1) return;
    float tv[32];
    const float4* ax = (const float4*)(acc + (size_t)node * 32);
#pragma unroll
    for (int c = 0; c < 8; ++c) {
        float4 v = ax[c];
        tv[c*4+0] = tanhf_(v.x); tv[c*4+1] = tanhf_(v.y);
        tv[c*4+2] = tanhf_(v.z); tv[c*4+3] = tanhf_(v.w);
    }
    float* orow = acc + (size_t)node * 32;
#pragma unroll
    for (int ob = 0; ob < 8; ++ob) {
        float o[4];
#pragma unroll
        for (int q = 0; q < 4; ++q) {
            int oj = ob * 4 + q;
            float a = b2[oj];
            const float4* w4 = (const float4*)(sW + oj * 32);
#pragma unroll
            for (int c = 0; c < 8; ++c) {
                float4 w = w4[c];
                a += tv[c*4+0]*w.x + tv[c*4+1]*w.y + tv[c*4+2]*w.z + tv[c*4+3]*w.w;
            }
            o[q] = a;
        }
        *(float4*)(orow + ob * 4) = make_float4(o[0], o[1], o[2], o[3]);
    }
}

// ---------------------------------------------------------------------------
// Fallback: atomic scatter (slow, correct; needs only n1*96*4 ws bytes)
// ---------------------------------------------------------------------------
template <int K>
__global__ __launch_bounds__(256) void gru_edges_atomic_noG(
    const int* __restrict__ idx, int nE,
    const float* __restrict__ h,
    const float* __restrict__ Wih, const float* __restrict__ bih,
    const float* __restrict__ Whh, const float* __restrict__ bhh,
    float* __restrict__ hk)
{
    int e = blockIdx.x * 256 + threadIdx.x;
    if (e >= nE) return;
    float hv[32];
#pragma unroll
    for (int t = 0; t < K; ++t) {
        int node = idx[(size_t)e * K + t];
        float x[32];
        const float4* hx = (const float4*)(h + (size_t)node * 32);
#pragma unroll
        for (int c = 0; c < 8; ++c) {
            float4 v = hx[c];
            x[c*4+0] = v.x; x[c*4+1] = v.y; x[c*4+2] = v.z; x[c*4+3] = v.w;
        }
        float hn_[32];
#pragma unroll
        for (int j = 0; j < 32; ++j) {
            float ir = bih[j], iz = bih[32 + j], in_ = bih[64 + j];
#pragma unroll
            for (int i = 0; i < 32; ++i) {
                ir  += x[i] * Wih[j * 32 + i];
                iz  += x[i] * Wih[(32 + j) * 32 + i];
                in_ += x[i] * Wih[(64 + j) * 32 + i];
            }
            float hr = bhh[j], hz = bhh[32 + j], hn2 = bhh[64 + j];
            if (t > 0) {
#pragma unroll
                for (int i = 0; i < 32; ++i) {
                    hr  += hv[i] * Whh[j * 32 + i];
                    hz  += hv[i] * Whh[(32 + j) * 32 + i];
                    hn2 += hv[i] * Whh[(64 + j) * 32 + i];
                }
            }
            float r = sigmoidf_(ir + hr);
            float z = sigmoidf_(iz + hz);
            float n = tanhf_(in_ + r * hn2);
            hn_[j] = (t > 0) ? ((1.0f - z) * n + z * hv[j]) : (1.0f - z) * n;
        }
        float* dst = hk + (size_t)node * 32;
#pragma unroll
        for (int j = 0; j < 32; ++j) {
            hv[j] = hn_[j];
            atomicAdd(dst + j, hn_[j]);
        }
    }
}

__global__ __launch_bounds__(256) void mlp_out_fb(
    const float* __restrict__ h, const float* __restrict__ hk, int n1,
    const float* __restrict__ W1, const float* __restrict__ b1,
    const float* __restrict__ W2, const float* __restrict__ b2,
    float* __restrict__ out)
{
    int node = blockIdx.x * 256 + threadIdx.x;
    if (node >= n1) return;
    float acc[32];
#pragma unroll
    for (int j = 0; j < 32; ++j) acc[j] = b1[j];
    const float* zsrc[4];
    zsrc[0] = h + (size_t)node * 32;
    zsrc[1] = hk + (size_t)node * 32;
    zsrc[2] = hk + (size_t)n1 * 32 + (size_t)node * 32;
    zsrc[3] = hk + (size_t)n1 * 64 + (size_t)node * 32;
#pragma unroll
    for (int m = 0; m < 4; ++m) {
        float zc[32];
        const float4* zp = (const float4*)zsrc[m];
#pragma unroll
        for (int c = 0; c < 8; ++c) {
            float4 v = zp[c];
            zc[c*4+0] = v.x; zc[c*4+1] = v.y; zc[c*4+2] = v.z; zc[c*4+3] = v.w;
        }
#pragma unroll
        for (int j = 0; j < 32; ++j) {
#pragma unroll
            for (int i = 0; i < 32; ++i)
                acc[j] += zc[i] * W1[j * 128 + m * 32 + i];
        }
    }
    float tv[32];
#pragma unroll
    for (int j = 0; j < 32; ++j) tv[j] = tanhf_(acc[j]);
    float* orow = out + (size_t)node * 32;
#pragma unroll
    for (int ob = 0; ob < 8; ++ob) {
        float o[4];
#pragma unroll
        for (int q = 0; q < 4; ++q) {
            int oj = ob * 4 + q;
            float a = b2[oj];
#pragma unroll
            for (int j = 0; j < 32; ++j)
                a += tv[j] * W2[oj * 32 + j];
            o[q] = a;
        }
        *(float4*)(orow + ob * 4) = make_float4(o[0], o[1], o[2], o[3]);
    }
}

// ---------------------------------------------------------------------------
static inline size_t alignUp(size_t x, size_t a) { return (x + a - 1) & ~(a - 1); }

extern "C" void kernel_launch(void* const* d_in, const int* in_sizes, int n_in,
                              void* d_out, int out_size, void* d_ws, size_t ws_size,
                              hipStream_t stream)
{
    const float* h    = (const float*)d_in[0];
    const int*   idx2 = (const int*)d_in[1];
    const int*   idx3 = (const int*)d_in[2];
    const int*   idx4 = (const int*)d_in[3];
    const float* Wih  = (const float*)d_in[4];
    const float* Whh  = (const float*)d_in[5];
    const float* bih  = (const float*)d_in[6];
    const float* bhh  = (const float*)d_in[7];
    const float* W1   = (const float*)d_in[8];
    const float* b1   = (const float*)d_in[9];
    const float* W2   = (const float*)d_in[10];
    const float* b2   = (const float*)d_in[11];
    float* out = (float*)d_out;

    int n1 = in_sizes[0] / 32;
    int n2 = in_sizes[1] / 2;
    int n3 = in_sizes[2] / 3;
    int n4 = in_sizes[3] / 4;
    int nEmax = n2 > n3 ? n2 : n3; if (n4 > nEmax) nEmax = n4;

    const int NCOL = 6;                       // k2:1 + k3:2 + k4:3 columns
    int M = NCOL * n1;                        // joint count/offs length
    int B0 = (M + 255) / 256;
    int B1 = (B0 + 255) / 256;
    size_t totE = (size_t)n2 + 2 * (size_t)n3 + 3 * (size_t)n4;

    // ---- workspace layout ----
    size_t off = 0;
    size_t h0Off  = off; off = alignUp(off + (size_t)n1 * 32 * 4, 256);
    size_t hsOff  = off; off = alignUp(off + (size_t)nEmax * 32 * 4, 256);
    size_t hkkOff = off; off = alignUp(off + (size_t)n1 * 32 * 4, 256);
    size_t cntOff = off; off = alignUp(off + (size_t)M * 4, 256);       // counts -> cursor
    size_t c0Off  = off; off = alignUp(off + (size_t)3 * n1 * 4, 256);  // cnt0 (3 k's)
    size_t oOff   = off; off = alignUp(off + (size_t)M * 4, 256);       // incl0 -> offs
    size_t entOff = off; off = alignUp(off + totE * 4, 256);
    size_t b0Off  = off; off = alignUp(off + (size_t)B0 * 4, 256);
    size_t i1Off  = off; off = alignUp(off + (size_t)B0 * 4, 256);
    size_t b1Off  = off; off = alignUp(off + (size_t)B1 * 4, 256);
    size_t need = off;

    int blocksN1 = (n1 + 255) / 256;
    char* ws = (char*)d_ws;

    if (ws_size >= need && B1 <= 1024) {
        float* h0     = (float*)(ws + h0Off);
        float* hstate = (float*)(ws + hsOff);
        float* hkk    = (float*)(ws + hkkOff);
        int*   counts = (int*)(ws + cntOff);   // later: cursor
        int*   cnt0   = (int*)(ws + c0Off);
        int*   offs   = (int*)(ws + oOff);     // incl0 -> finalize in place
        int*   ent    = (int*)(ws + entOff);
        int*   bsums0 = (int*)(ws + b0Off);
        int*   incl1  = (int*)(ws + i1Off);
        int*   bsums1 = (int*)(ws + b1Off);

        // --- CSR build (batched, joint scan over 6 columns) ---
        hipMemsetAsync(counts, 0, ((size_t)M + 3 * n1) * 4, stream); // counts+cnt0 adjacent
        hist_all<2><<<(n2 * 2 + 255) / 256, 256, 0, stream>>>(idx2, n2 * 2, cnt0,          counts,          n1);
        hist_all<3><<<(n3 * 3 + 255) / 256, 256, 0, stream>>>(idx3, n3 * 3, cnt0 + n1,     counts + n1,     n1);
        hist_all<4><<<(n4 * 4 + 255) / 256, 256, 0, stream>>>(idx4, n4 * 4, cnt0 + 2 * n1, counts + 3 * n1, n1);
        scan_block<<<B0, 256, 0, stream>>>(counts, offs, bsums0, M);
        scan_block<<<B1, 256, 0, stream>>>(bsums0, incl1, bsums1, B0);
        scan_bsums<<<1, 1024, 0, stream>>>(bsums1, B1);
        finalize_joint<<<B0, 256, 0, stream>>>(offs, counts, bsums0, incl1, bsums1, M);
        hipMemcpyAsync(counts, offs, (size_t)M * 4, hipMemcpyDeviceToDevice, stream); // cursor = offs
        fill_all<2><<<(n2 * 1 + 255) / 256, 256, 0, stream>>>(idx2, n2 * 1, counts,          ent, n1);
        fill_all<3><<<(n3 * 2 + 255) / 256, 256, 0, stream>>>(idx3, n3 * 2, counts + n1,     ent, n1);
        fill_all<4><<<(n4 * 3 + 255) / 256, 256, 0, stream>>>(idx4, n4 * 3, counts + 3 * n1, ent, n1);

        // --- node-side precomputes ---
        compute_h0<<<blocksN1, 256, 0, stream>>>(h, Wih, bih, bhh, h0, n1);
        init_acc<<<blocksN1, 256, 0, stream>>>(h, W1, b1, out, n1);

        // --- per-k pipeline ---
        const int* idxs[3] = { idx2, idx3, idx4 };
        int nEs[3] = { n2, n3, n4 };
        int colbase[3] = { 0, 1, 3 };
        int gaBlocks = ((n1 * 8) + 255) / 256;

        for (int kk = 0; kk < 3; ++kk) {
            const int* idx = idxs[kk];
            int nE = nEs[kk];
            int blocksE2 = (nE + 511) / 512;   // 2 edges per thread

            init_hkk<<<gaBlocks, 256, 0, stream>>>(cnt0 + kk * n1, h0, hkk, n1);

            int K = kk + 2;
            for (int t = 1; t < K; ++t) {
                if (K == 2)      gru_step_h<2, 1><<<blocksE2, 256, 0, stream>>>(idx, nE, h, h0, Wih, bih, Whh, bhh, hstate);
                else if (K == 3) {
                    if (t == 1)  gru_step_h<3, 1><<<blocksE2, 256, 0, stream>>>(idx, nE, h, h0, Wih, bih, Whh, bhh, hstate);
                    else         gru_step_h<3, 2><<<blocksE2, 256, 0, stream>>>(idx, nE, h, h0, Wih, bih, Whh, bhh, hstate);
                } else {
                    if (t == 1)      gru_step_h<4, 1><<<blocksE2, 256, 0, stream>>>(idx, nE, h, h0, Wih, bih, Whh, bhh, hstate);
                    else if (t == 2) gru_step_h<4, 2><<<blocksE2, 256, 0, stream>>>(idx, nE, h, h0, Wih, bih, Whh, bhh, hstate);
                    else             gru_step_h<4, 3><<<blocksE2, 256, 0, stream>>>(idx, nE, h, h0, Wih, bih, Whh, bhh, hstate);
                }
                int col = colbase[kk] + (t - 1);
                gather_add<<<gaBlocks, 256, 0, stream>>>(
                    offs + (size_t)col * n1, counts + (size_t)col * n1,
                    ent, hstate, hkk, n1);
            }

            fold_w1<<<blocksN1, 256, 0, stream>>>(hkk, W1 + (kk + 1) * 32, out, n1);
        }

        finish_out<<<blocksN1, 256, 0, stream>>>(out, W2, b2, n1);
        return;
    }

    // ===== fallback: atomic path, hk only (n1*96*4 bytes) =====
    float* hk = (float*)d_ws;
    hipMemsetAsync(d_ws, 0, (size_t)n1 * 96 * 4, stream);
    gru_edges_atomic_noG<2><<<(n2 + 255) / 256, 256, 0, stream>>>(
        idx2, n2, h, Wih, bih, Whh, bhh, hk);
    gru_edges_atomic_noG<3><<<(n3 + 255) / 256, 256, 0, stream>>>(
        idx3, n3, h, Wih, bih, Whh, bhh, hk + (size_t)n1 * 32);
    gru_edges_atomic_noG<4><<<(n4 + 255) / 256, 256, 0, stream>>>(
        idx4, n4, h, Wih, bih, Whh, bhh, hk + (size_t)n1 * 64);
    mlp_out_fb<<<blocksN1, 256, 0, stream>>>(h, hk, n1, W1, b1, W2, b2, out);
}

// Round 10
// 10580.343 us; speedup vs baseline: 1.9917x; 1.9917x over previous
//
#include <hip/hip_runtime.h>
#include <hip/hip_bf16.h>

__device__ __forceinline__ float sigmoidf_(float x) {
    return 1.0f / (1.0f + __expf(-x));
}
__device__ __forceinline__ float tanhf_(float x) {
    float e = __expf(2.0f * x);
    return 1.0f - 2.0f / (e + 1.0f);
}

#define FMA4(acc, a, b) \
    acc.x = fmaf(a.x, b.x, acc.x); acc.y = fmaf(a.y, b.y, acc.y); \
    acc.z = fmaf(a.z, b.z, acc.z); acc.w = fmaf(a.w, b.w, acc.w);
#define HS(v) (((v).x + (v).y) + ((v).z + (v).w))

// ---------------------------------------------------------------------------
// h0[node] = GRU step with hprev=0 (gh = bhh). Wih staged in LDS.
// ---------------------------------------------------------------------------
__global__ __launch_bounds__(256) void compute_h0(
    const float* __restrict__ h, const float* __restrict__ Wih,
    const float* __restrict__ bih, const float* __restrict__ bhh,
    float* __restrict__ h0, int n1)
{
    __shared__ float sW[3072];
    __shared__ float sB[192];
    {
        const float4* a4 = (const float4*)Wih;
        float4* sa = (float4*)sW;
#pragma unroll
        for (int c = 0; c < 3; ++c)
            sa[c * 256 + threadIdx.x] = a4[c * 256 + threadIdx.x];
        if (threadIdx.x < 192)
            sB[threadIdx.x] = (threadIdx.x < 96) ? bih[threadIdx.x]
                                                 : bhh[threadIdx.x - 96];
    }
    __syncthreads();

    int node = blockIdx.x * 256 + threadIdx.x;
    if (node >= n1) return;
    float x[32];
    const float4* hx = (const float4*)(h + (size_t)node * 32);
#pragma unroll
    for (int c = 0; c < 8; ++c) {
        float4 v = hx[c];
        x[c*4+0] = v.x; x[c*4+1] = v.y; x[c*4+2] = v.z; x[c*4+3] = v.w;
    }
    float o[32];
#pragma unroll
    for (int j = 0; j < 32; ++j) {
        float ir = sB[j], iz = sB[32 + j], in_ = sB[64 + j];
        const float4* wr = (const float4*)(sW + j * 32);
        const float4* wz = (const float4*)(sW + (32 + j) * 32);
        const float4* wn = (const float4*)(sW + (64 + j) * 32);
#pragma unroll
        for (int c = 0; c < 8; ++c) {
            float4 a = wr[c], b = wz[c], d = wn[c];
            ir  += x[c*4+0]*a.x + x[c*4+1]*a.y + x[c*4+2]*a.z + x[c*4+3]*a.w;
            iz  += x[c*4+0]*b.x + x[c*4+1]*b.y + x[c*4+2]*b.z + x[c*4+3]*b.w;
            in_ += x[c*4+0]*d.x + x[c*4+1]*d.y + x[c*4+2]*d.z + x[c*4+3]*d.w;
        }
        float r = sigmoidf_(ir + sB[96 + j]);
        float z = sigmoidf_(iz + sB[128 + j]);
        float n = tanhf_(in_ + r * sB[160 + j]);
        o[j] = (1.0f - z) * n;
    }
    float4* dst = (float4*)(h0 + (size_t)node * 32);
#pragma unroll
    for (int c = 0; c < 8; ++c)
        dst[c] = make_float4(o[c*4+0], o[c*4+1], o[c*4+2], o[c*4+3]);
}

// ---------------------------------------------------------------------------
// Batched histogram per k-list
// ---------------------------------------------------------------------------
template <int K>
__global__ __launch_bounds__(256) void hist_all(
    const int* __restrict__ idx, int nI, int* __restrict__ cnt0,
    int* __restrict__ counts, int n1)
{
    int i = blockIdx.x * 256 + threadIdx.x;
    if (i >= nI) return;
    int t = i % K;
    int node = idx[i];
    if (t == 0) atomicAdd(&cnt0[node], 1);
    else        atomicAdd(&counts[(size_t)(t - 1) * n1 + node], 1);
}

// ---------------------------------------------------------------------------
// Scan machinery (3-level)
// ---------------------------------------------------------------------------
__global__ __launch_bounds__(256) void scan_block(
    const int* __restrict__ in, int* __restrict__ incl,
    int* __restrict__ bsums, int n)
{
    __shared__ int s[256];
    int i = blockIdx.x * 256 + threadIdx.x;
    int v = (i < n) ? in[i] : 0;
    s[threadIdx.x] = v;
    __syncthreads();
    for (int d = 1; d < 256; d <<= 1) {
        int tt = (threadIdx.x >= d) ? s[threadIdx.x - d] : 0;
        __syncthreads();
        s[threadIdx.x] += tt;
        __syncthreads();
    }
    if (i < n) incl[i] = s[threadIdx.x];
    if (threadIdx.x == 255) bsums[blockIdx.x] = s[255];
}

__global__ __launch_bounds__(1024) void scan_bsums(int* bsums, int nb)
{
    __shared__ int s[1024];
    int v = (threadIdx.x < nb) ? bsums[threadIdx.x] : 0;
    s[threadIdx.x] = v;
    __syncthreads();
    for (int d = 1; d < 1024; d <<= 1) {
        int tt = (threadIdx.x >= d) ? s[threadIdx.x - d] : 0;
        __syncthreads();
        s[threadIdx.x] += tt;
        __syncthreads();
    }
    if (threadIdx.x < nb) bsums[threadIdx.x] = s[threadIdx.x] - v; // exclusive
}

__global__ __launch_bounds__(256) void finalize_joint(
    int* __restrict__ offs, const int* __restrict__ counts,
    const int* __restrict__ bsums0, const int* __restrict__ incl1,
    const int* __restrict__ bsums1ex, int M)
{
    int i = blockIdx.x * 256 + threadIdx.x;
    if (i >= M) return;
    int b0 = i >> 8, b1 = b0 >> 8;
    offs[i] = offs[i] - counts[i] + (incl1[b0] - bsums0[b0]) + bsums1ex[b1];
}

template <int K>
__global__ __launch_bounds__(256) void fill_all(
    const int* __restrict__ idx, int nW,
    int* __restrict__ cursor, int* __restrict__ ent, int n1)
{
    int i = blockIdx.x * 256 + threadIdx.x;
    if (i >= nW) return;
    int e = i / (K - 1), tt = i % (K - 1);
    int node = idx[(size_t)e * K + tt + 1];
    int p = atomicAdd(&cursor[(size_t)tt * n1 + node], 1);
    ent[p] = e;
}

// ---------------------------------------------------------------------------
// One GRU step (t = T >= 1), 2 edges/thread. All state in float4 arrays with
// STATIC indices only (unrolled jb / macro-expanded q / unrolled c) — spill-
// proof per rule #20. Weights+biases in LDS (broadcast reads).
// ---------------------------------------------------------------------------
template <int K, int T>
__global__ __launch_bounds__(256) void gru_step_h(
    const int* __restrict__ idx, int nE,
    const float* __restrict__ h, const float* __restrict__ h0,
    const float* __restrict__ Wih, const float* __restrict__ bih,
    const float* __restrict__ Whh, const float* __restrict__ bhh,
    float* __restrict__ hstate)
{
    __shared__ float sWih[3072];
    __shared__ float sWhh[3072];
    __shared__ float sB[192];
    {
        const float4* a4 = (const float4*)Wih;
        const float4* b4 = (const float4*)Whh;
        float4* sa = (float4*)sWih;
        float4* sb = (float4*)sWhh;
#pragma unroll
        for (int c = 0; c < 3; ++c) {
            sa[c * 256 + threadIdx.x] = a4[c * 256 + threadIdx.x];
            sb[c * 256 + threadIdx.x] = b4[c * 256 + threadIdx.x];
        }
        if (threadIdx.x < 192)
            sB[threadIdx.x] = (threadIdx.x < 96) ? bih[threadIdx.x]
                                                 : bhh[threadIdx.x - 96];
    }
    __syncthreads();

    int e0 = blockIdx.x * 512 + threadIdx.x;
    if (e0 >= nE) return;
    int e1 = e0 + 256;
    bool v1 = (e1 < nE);
    int e1c = v1 ? e1 : e0;

    float4 X0[8], X1[8], H0[8], H1[8];
    if (T == 1) {
        int a0 = idx[(size_t)e0 * K];
        int a1 = idx[(size_t)e1c * K];
        const float4* p0 = (const float4*)(h0 + (size_t)a0 * 32);
        const float4* p1 = (const float4*)(h0 + (size_t)a1 * 32);
#pragma unroll
        for (int c = 0; c < 8; ++c) { H0[c] = p0[c]; H1[c] = p1[c]; }
    } else {
        const float4* p0 = (const float4*)(hstate + (size_t)e0 * 32);
        const float4* p1 = (const float4*)(hstate + (size_t)e1c * 32);
#pragma unroll
        for (int c = 0; c < 8; ++c) { H0[c] = p0[c]; H1[c] = p1[c]; }
    }
    {
        int n0 = idx[(size_t)e0 * K + T];
        int nn1 = idx[(size_t)e1c * K + T];
        const float4* p0 = (const float4*)(h + (size_t)n0 * 32);
        const float4* p1 = (const float4*)(h + (size_t)nn1 * 32);
#pragma unroll
        for (int c = 0; c < 8; ++c) { X0[c] = p0[c]; X1[c] = p1[c]; }
    }

    float4* hs0 = (float4*)(hstate + (size_t)e0 * 32);
    float4* hs1 = (float4*)(hstate + (size_t)e1 * 32);
    const float4 z4 = make_float4(0.f, 0.f, 0.f, 0.f);

#define GATE_Q(Q, CMP)                                                        \
    {                                                                         \
        const int j = jb * 4 + Q;                                             \
        const float4* wr = (const float4*)(sWih + j * 32);                    \
        const float4* wz = (const float4*)(sWih + (32 + j) * 32);             \
        const float4* wn = (const float4*)(sWih + (64 + j) * 32);             \
        const float4* ur = (const float4*)(sWhh + j * 32);                    \
        const float4* uz = (const float4*)(sWhh + (32 + j) * 32);             \
        const float4* un = (const float4*)(sWhh + (64 + j) * 32);             \
        float4 a_ir = z4, a_iz = z4, a_in = z4, a_hr = z4, a_hz = z4, a_hn = z4; \
        float4 b_ir = z4, b_iz = z4, b_in = z4, b_hr = z4, b_hz = z4, b_hn = z4; \
        _Pragma("unroll")                                                     \
        for (int c = 0; c < 8; ++c) {                                         \
            float4 w0 = wr[c], w1 = wz[c], w2 = wn[c];                        \
            float4 u0 = ur[c], u1 = uz[c], u2 = un[c];                        \
            float4 xa = X0[c], ha = H0[c], xb = X1[c], hb = H1[c];            \
            FMA4(a_ir, xa, w0) FMA4(a_iz, xa, w1) FMA4(a_in, xa, w2)          \
            FMA4(a_hr, ha, u0) FMA4(a_hz, ha, u1) FMA4(a_hn, ha, u2)          \
            FMA4(b_ir, xb, w0) FMA4(b_iz, xb, w1) FMA4(b_in, xb, w2)          \
            FMA4(b_hr, hb, u0) FMA4(b_hz, hb, u1) FMA4(b_hn, hb, u2)          \
        }                                                                     \
        {                                                                     \
            float rr = sigmoidf_((HS(a_ir) + sB[j]) + (HS(a_hr) + sB[96 + j])); \
            float zz = sigmoidf_((HS(a_iz) + sB[32 + j]) + (HS(a_hz) + sB[128 + j])); \
            float nn = tanhf_((HS(a_in) + sB[64 + j]) + rr * (HS(a_hn) + sB[160 + j])); \
            o0.CMP = (1.0f - zz) * nn + zz * H0[jb].CMP;                      \
        }                                                                     \
        {                                                                     \
            float rr = sigmoidf_((HS(b_ir) + sB[j]) + (HS(b_hr) + sB[96 + j])); \
            float zz = sigmoidf_((HS(b_iz) + sB[32 + j]) + (HS(b_hz) + sB[128 + j])); \
            float nn = tanhf_((HS(b_in) + sB[64 + j]) + rr * (HS(b_hn) + sB[160 + j])); \
            o1.CMP = (1.0f - zz) * nn + zz * H1[jb].CMP;                      \
        }                                                                     \
    }

#pragma unroll
    for (int jb = 0; jb < 8; ++jb) {
        float4 o0, o1;
        GATE_Q(0, x)
        GATE_Q(1, y)
        GATE_Q(2, z)
        GATE_Q(3, w)
        hs0[jb] = o0;
        if (v1) hs1[jb] = o1;
    }
#undef GATE_Q
}

// ---------------------------------------------------------------------------
// hkk[node] = cnt0[node] * h0[node]
// ---------------------------------------------------------------------------
__global__ __launch_bounds__(256) void init_hkk(
    const int* __restrict__ cnt0, const float* __restrict__ h0,
    float* __restrict__ hkk, int n1)
{
    int gid = blockIdx.x * 256 + threadIdx.x;
    int node = gid >> 3;
    int sub = gid & 7;
    if (node >= n1) return;
    float c = (float)cnt0[node];
    float4 v = *(const float4*)(h0 + (size_t)node * 32 + sub * 4);
    v.x *= c; v.y *= c; v.z *= c; v.w *= c;
    *(float4*)(hkk + (size_t)node * 32 + sub * 4) = v;
}

// ---------------------------------------------------------------------------
// hkk[node] += sum over entries of hstate rows. 8 threads/node, no atomics.
// ---------------------------------------------------------------------------
__global__ __launch_bounds__(256) void gather_add(
    const int* __restrict__ offs, const int* __restrict__ endp,
    const int* __restrict__ ent,
    const float* __restrict__ hstate, float* __restrict__ hkk, int n1)
{
    int gid = blockIdx.x * 256 + threadIdx.x;
    int node = gid >> 3;
    int sub = gid & 7;
    if (node >= n1) return;
    int beg = offs[node], end = endp[node];
    if (beg == end) return;
    float4 a = make_float4(0.f, 0.f, 0.f, 0.f);
    for (int p = beg; p < end; ++p) {
        int e = ent[p];
        float4 v = *(const float4*)(hstate + (size_t)e * 32 + sub * 4);
        a.x += v.x; a.y += v.y; a.z += v.z; a.w += v.w;
    }
    float* dst = hkk + (size_t)node * 32 + sub * 4;
    float4 cur = *(float4*)dst;
    cur.x += a.x; cur.y += a.y; cur.z += a.z; cur.w += a.w;
    *(float4*)dst = cur;
}

// ---------------------------------------------------------------------------
// acc(=out)[node] = b1 + h[node] @ W1[:,0:32].T
// ---------------------------------------------------------------------------
__global__ __launch_bounds__(256) void init_acc(
    const float* __restrict__ h, const float* __restrict__ W1,
    const float* __restrict__ b1, float* __restrict__ acc, int n1)
{
    __shared__ float sW[1024];
#pragma unroll
    for (int c = 0; c < 4; ++c) {
        int i = c * 256 + threadIdx.x;
        sW[i] = W1[(i >> 5) * 128 + (i & 31)];
    }
    __syncthreads();

    int node = blockIdx.x * 256 + threadIdx.x;
    if (node >= n1) return;
    float x[32];
    const float4* hx = (const float4*)(h + (size_t)node * 32);
#pragma unroll
    for (int c = 0; c < 8; ++c) {
        float4 v = hx[c];
        x[c*4+0] = v.x; x[c*4+1] = v.y; x[c*4+2] = v.z; x[c*4+3] = v.w;
    }
    float* arow = acc + (size_t)node * 32;
#pragma unroll
    for (int jb = 0; jb < 8; ++jb) {
        float o[4];
#pragma unroll
        for (int q = 0; q < 4; ++q) {
            int j = jb * 4 + q;
            float a = b1[j];
            const float4* w4 = (const float4*)(sW + j * 32);
#pragma unroll
            for (int c = 0; c < 8; ++c) {
                float4 w = w4[c];
                a += x[c*4+0]*w.x + x[c*4+1]*w.y + x[c*4+2]*w.z + x[c*4+3]*w.w;
            }
            o[q] = a;
        }
        *(float4*)(arow + jb * 4) = make_float4(o[0], o[1], o[2], o[3]);
    }
}

// ---------------------------------------------------------------------------
// acc(=out)[node] += hkk[node] @ W1blk.T
// ---------------------------------------------------------------------------
__global__ __launch_bounds__(256) void fold_w1(
    const float* __restrict__ hkk, const float* __restrict__ W1blk,
    float* __restrict__ acc, int n1)
{
    __shared__ float sW[1024];
#pragma unroll
    for (int c = 0; c < 4; ++c) {
        int i = c * 256 + threadIdx.x;
        sW[i] = W1blk[(i >> 5) * 128 + (i & 31)];
    }
    __syncthreads();

    int node = blockIdx.x * 256 + threadIdx.x;
    if (node >= n1) return;
    float x[32];
    const float4* hx = (const float4*)(hkk + (size_t)node * 32);
#pragma unroll
    for (int c = 0; c < 8; ++c) {
        float4 v = hx[c];
        x[c*4+0] = v.x; x[c*4+1] = v.y; x[c*4+2] = v.z; x[c*4+3] = v.w;
    }
    float* arow = acc + (size_t)node * 32;
#pragma unroll
    for (int jb = 0; jb < 8; ++jb) {
        float4 cur = *(float4*)(arow + jb * 4);
        float o[4] = { cur.x, cur.y, cur.z, cur.w };
#pragma unroll
        for (int q = 0; q < 4; ++q) {
            int j = jb * 4 + q;
            float a = o[q];
            const float4* w4 = (const float4*)(sW + j * 32);
#pragma unroll
            for (int c = 0; c < 8; ++c) {
                float4 w = w4[c];
                a += x[c*4+0]*w.x + x[c*4+1]*w.y + x[c*4+2]*w.z + x[c*4+3]*w.w;
            }
            o[q] = a;
        }
        *(float4*)(arow + jb * 4) = make_float4(o[0], o[1], o[2], o[3]);
    }
}

// ---------------------------------------------------------------------------
// out[node] = tanh(acc[node]) @ W2.T + b2   (in-place)
// ---------------------------------------------------------------------------
__global__ __launch_bounds__(256) void finish_out(
    float* __restrict__ acc, const float* __restrict__ W2,
    const float* __restrict__ b2, int n1)
{
    __shared__ float sW[1024];
    {
        const float4* w4 = (const float4*)W2;
        float4* s4 = (float4*)sW;
        if (threadIdx.x < 256) s4[threadIdx.x] = w4[threadIdx.x];
    }
    __syncthreads();

    int node = blockIdx.x * 256 + threadIdx.x;
    if (node >= n1) return;
    float tv[32];
    const float4* ax = (const float4*)(acc + (size_t)node * 32);
#pragma unroll
    for (int c = 0; c < 8; ++c) {
        float4 v = ax[c];
        tv[c*4+0] = tanhf_(v.x); tv[c*4+1] = tanhf_(v.y);
        tv[c*4+2] = tanhf_(v.z); tv[c*4+3] = tanhf_(v.w);
    }
    float* orow = acc + (size_t)node * 32;
#pragma unroll
    for (int ob = 0; ob < 8; ++ob) {
        float o[4];
#pragma unroll
        for (int q = 0; q < 4; ++q) {
            int oj = ob * 4 + q;
            float a = b2[oj];
            const float4* w4 = (const float4*)(sW + oj * 32);
#pragma unroll
            for (int c = 0; c < 8; ++c) {
                float4 w = w4[c];
                a += tv[c*4+0]*w.x + tv[c*4+1]*w.y + tv[c*4+2]*w.z + tv[c*4+3]*w.w;
            }
            o[q] = a;
        }
        *(float4*)(orow + ob * 4) = make_float4(o[0], o[1], o[2], o[3]);
    }
}

// ---------------------------------------------------------------------------
// Fallback: atomic scatter (slow, correct)
// ---------------------------------------------------------------------------
template <int K>
__global__ __launch_bounds__(256) void gru_edges_atomic_noG(
    const int* __restrict__ idx, int nE,
    const float* __restrict__ h,
    const float* __restrict__ Wih, const float* __restrict__ bih,
    const float* __restrict__ Whh, const float* __restrict__ bhh,
    float* __restrict__ hk)
{
    int e = blockIdx.x * 256 + threadIdx.x;
    if (e >= nE) return;
    float hv[32];
#pragma unroll
    for (int t = 0; t < K; ++t) {
        int node = idx[(size_t)e * K + t];
        float x[32];
        const float4* hx = (const float4*)(h + (size_t)node * 32);
#pragma unroll
        for (int c = 0; c < 8; ++c) {
            float4 v = hx[c];
            x[c*4+0] = v.x; x[c*4+1] = v.y; x[c*4+2] = v.z; x[c*4+3] = v.w;
        }
        float hn_[32];
#pragma unroll
        for (int j = 0; j < 32; ++j) {
            float ir = bih[j], iz = bih[32 + j], in_ = bih[64 + j];
#pragma unroll
            for (int i = 0; i < 32; ++i) {
                ir  += x[i] * Wih[j * 32 + i];
                iz  += x[i] * Wih[(32 + j) * 32 + i];
                in_ += x[i] * Wih[(64 + j) * 32 + i];
            }
            float hr = bhh[j], hz = bhh[32 + j], hn2 = bhh[64 + j];
            if (t > 0) {
#pragma unroll
                for (int i = 0; i < 32; ++i) {
                    hr  += hv[i] * Whh[j * 32 + i];
                    hz  += hv[i] * Whh[(32 + j) * 32 + i];
                    hn2 += hv[i] * Whh[(64 + j) * 32 + i];
                }
            }
            float r = sigmoidf_(ir + hr);
            float z = sigmoidf_(iz + hz);
            float n = tanhf_(in_ + r * hn2);
            hn_[j] = (t > 0) ? ((1.0f - z) * n + z * hv[j]) : (1.0f - z) * n;
        }
        float* dst = hk + (size_t)node * 32;
#pragma unroll
        for (int j = 0; j < 32; ++j) {
            hv[j] = hn_[j];
            atomicAdd(dst + j, hn_[j]);
        }
    }
}

__global__ __launch_bounds__(256) void mlp_out_fb(
    const float* __restrict__ h, const float* __restrict__ hk, int n1,
    const float* __restrict__ W1, const float* __restrict__ b1,
    const float* __restrict__ W2, const float* __restrict__ b2,
    float* __restrict__ out)
{
    int node = blockIdx.x * 256 + threadIdx.x;
    if (node >= n1) return;
    float acc[32];
#pragma unroll
    for (int j = 0; j < 32; ++j) acc[j] = b1[j];
    const float* zsrc[4];
    zsrc[0] = h + (size_t)node * 32;
    zsrc[1] = hk + (size_t)node * 32;
    zsrc[2] = hk + (size_t)n1 * 32 + (size_t)node * 32;
    zsrc[3] = hk + (size_t)n1 * 64 + (size_t)node * 32;
#pragma unroll
    for (int m = 0; m < 4; ++m) {
        float zc[32];
        const float4* zp = (const float4*)zsrc[m];
#pragma unroll
        for (int c = 0; c < 8; ++c) {
            float4 v = zp[c];
            zc[c*4+0] = v.x; zc[c*4+1] = v.y; zc[c*4+2] = v.z; zc[c*4+3] = v.w;
        }
#pragma unroll
        for (int j = 0; j < 32; ++j) {
#pragma unroll
            for (int i = 0; i < 32; ++i)
                acc[j] += zc[i] * W1[j * 128 + m * 32 + i];
        }
    }
    float tv[32];
#pragma unroll
    for (int j = 0; j < 32; ++j) tv[j] = tanhf_(acc[j]);
    float* orow = out + (size_t)node * 32;
#pragma unroll
    for (int ob = 0; ob < 8; ++ob) {
        float o[4];
#pragma unroll
        for (int q = 0; q < 4; ++q) {
            int oj = ob * 4 + q;
            float a = b2[oj];
#pragma unroll
            for (int j = 0; j < 32; ++j)
                a += tv[j] * W2[oj * 32 + j];
            o[q] = a;
        }
        *(float4*)(orow + ob * 4) = make_float4(o[0], o[1], o[2], o[3]);
    }
}

// ---------------------------------------------------------------------------
static inline size_t alignUp(size_t x, size_t a) { return (x + a - 1) & ~(a - 1); }

extern "C" void kernel_launch(void* const* d_in, const int* in_sizes, int n_in,
                              void* d_out, int out_size, void* d_ws, size_t ws_size,
                              hipStream_t stream)
{
    const float* h    = (const float*)d_in[0];
    const int*   idx2 = (const int*)d_in[1];
    const int*   idx3 = (const int*)d_in[2];
    const int*   idx4 = (const int*)d_in[3];
    const float* Wih  = (const float*)d_in[4];
    const float* Whh  = (const float*)d_in[5];
    const float* bih  = (const float*)d_in[6];
    const float* bhh  = (const float*)d_in[7];
    const float* W1   = (const float*)d_in[8];
    const float* b1   = (const float*)d_in[9];
    const float* W2   = (const float*)d_in[10];
    const float* b2   = (const float*)d_in[11];
    float* out = (float*)d_out;

    int n1 = in_sizes[0] / 32;
    int n2 = in_sizes[1] / 2;
    int n3 = in_sizes[2] / 3;
    int n4 = in_sizes[3] / 4;
    int nEmax = n2 > n3 ? n2 : n3; if (n4 > nEmax) nEmax = n4;

    const int NCOL = 6;
    int M = NCOL * n1;
    int B0 = (M + 255) / 256;
    int B1 = (B0 + 255) / 256;
    size_t totE = (size_t)n2 + 2 * (size_t)n3 + 3 * (size_t)n4;

    // ---- workspace layout ----
    size_t off = 0;
    size_t h0Off  = off; off = alignUp(off + (size_t)n1 * 32 * 4, 256);
    size_t hsOff  = off; off = alignUp(off + (size_t)nEmax * 32 * 4, 256);
    size_t hkkOff = off; off = alignUp(off + (size_t)n1 * 32 * 4, 256);
    size_t cntOff = off; off = alignUp(off + (size_t)M * 4, 256);
    size_t c0Off  = off; off = alignUp(off + (size_t)3 * n1 * 4, 256);
    size_t oOff   = off; off = alignUp(off + (size_t)M * 4, 256);
    size_t entOff = off; off = alignUp(off + totE * 4, 256);
    size_t b0Off  = off; off = alignUp(off + (size_t)B0 * 4, 256);
    size_t i1Off  = off; off = alignUp(off + (size_t)B0 * 4, 256);
    size_t b1Off  = off; off = alignUp(off + (size_t)B1 * 4, 256);
    size_t need = off;

    int blocksN1 = (n1 + 255) / 256;
    char* ws = (char*)d_ws;

    if (ws_size >= need && B1 <= 1024) {
        float* h0     = (float*)(ws + h0Off);
        float* hstate = (float*)(ws + hsOff);
        float* hkk    = (float*)(ws + hkkOff);
        int*   counts = (int*)(ws + cntOff);
        int*   cnt0   = (int*)(ws + c0Off);
        int*   offs   = (int*)(ws + oOff);
        int*   ent    = (int*)(ws + entOff);
        int*   bsums0 = (int*)(ws + b0Off);
        int*   incl1  = (int*)(ws + i1Off);
        int*   bsums1 = (int*)(ws + b1Off);

        // --- CSR build ---
        hipMemsetAsync(counts, 0, ((size_t)M + 3 * n1) * 4, stream);
        hist_all<2><<<(n2 * 2 + 255) / 256, 256, 0, stream>>>(idx2, n2 * 2, cnt0,          counts,          n1);
        hist_all<3><<<(n3 * 3 + 255) / 256, 256, 0, stream>>>(idx3, n3 * 3, cnt0 + n1,     counts + n1,     n1);
        hist_all<4><<<(n4 * 4 + 255) / 256, 256, 0, stream>>>(idx4, n4 * 4, cnt0 + 2 * n1, counts + 3 * n1, n1);
        scan_block<<<B0, 256, 0, stream>>>(counts, offs, bsums0, M);
        scan_block<<<B1, 256, 0, stream>>>(bsums0, incl1, bsums1, B0);
        scan_bsums<<<1, 1024, 0, stream>>>(bsums1, B1);
        finalize_joint<<<B0, 256, 0, stream>>>(offs, counts, bsums0, incl1, bsums1, M);
        hipMemcpyAsync(counts, offs, (size_t)M * 4, hipMemcpyDeviceToDevice, stream);
        fill_all<2><<<(n2 * 1 + 255) / 256, 256, 0, stream>>>(idx2, n2 * 1, counts,          ent, n1);
        fill_all<3><<<(n3 * 2 + 255) / 256, 256, 0, stream>>>(idx3, n3 * 2, counts + n1,     ent, n1);
        fill_all<4><<<(n4 * 3 + 255) / 256, 256, 0, stream>>>(idx4, n4 * 3, counts + 3 * n1, ent, n1);

        // --- node-side precomputes ---
        compute_h0<<<blocksN1, 256, 0, stream>>>(h, Wih, bih, bhh, h0, n1);
        init_acc<<<blocksN1, 256, 0, stream>>>(h, W1, b1, out, n1);

        // --- per-k pipeline ---
        const int* idxs[3] = { idx2, idx3, idx4 };
        int nEs[3] = { n2, n3, n4 };
        int colbase[3] = { 0, 1, 3 };
        int gaBlocks = ((n1 * 8) + 255) / 256;

        for (int kk = 0; kk < 3; ++kk) {
            const int* idx = idxs[kk];
            int nE = nEs[kk];
            int blocksE2 = (nE + 511) / 512;   // 2 edges per thread

            init_hkk<<<gaBlocks, 256, 0, stream>>>(cnt0 + kk * n1, h0, hkk, n1);

            int K = kk + 2;
            for (int t = 1; t < K; ++t) {
                if (K == 2)      gru_step_h<2, 1><<<blocksE2, 256, 0, stream>>>(idx, nE, h, h0, Wih, bih, Whh, bhh, hstate);
                else if (K == 3) {
                    if (t == 1)  gru_step_h<3, 1><<<blocksE2, 256, 0, stream>>>(idx, nE, h, h0, Wih, bih, Whh, bhh, hstate);
                    else         gru_step_h<3, 2><<<blocksE2, 256, 0, stream>>>(idx, nE, h, h0, Wih, bih, Whh, bhh, hstate);
                } else {
                    if (t == 1)      gru_step_h<4, 1><<<blocksE2, 256, 0, stream>>>(idx, nE, h, h0, Wih, bih, Whh, bhh, hstate);
                    else if (t == 2) gru_step_h<4, 2><<<blocksE2, 256, 0, stream>>>(idx, nE, h, h0, Wih, bih, Whh, bhh, hstate);
                    else             gru_step_h<4, 3><<<blocksE2, 256, 0, stream>>>(idx, nE, h, h0, Wih, bih, Whh, bhh, hstate);
                }
                int col = colbase[kk] + (t - 1);
                gather_add<<<gaBlocks, 256, 0, stream>>>(
                    offs + (size_t)col * n1, counts + (size_t)col * n1,
                    ent, hstate, hkk, n1);
            }

            fold_w1<<<blocksN1, 256, 0, stream>>>(hkk, W1 + (kk + 1) * 32, out, n1);
        }

        finish_out<<<blocksN1, 256, 0, stream>>>(out, W2, b2, n1);
        return;
    }

    // ===== fallback: atomic path =====
    float* hk = (float*)d_ws;
    hipMemsetAsync(d_ws, 0, (size_t)n1 * 96 * 4, stream);
    gru_edges_atomic_noG<2><<<(n2 + 255) / 256, 256, 0, stream>>>(
        idx2, n2, h, Wih, bih, Whh, bhh, hk);
    gru_edges_atomic_noG<3><<<(n3 + 255) / 256, 256, 0, stream>>>(
        idx3, n3, h, Wih, bih, Whh, bhh, hk + (size_t)n1 * 32);
    gru_edges_atomic_noG<4><<<(n4 + 255) / 256, 256, 0, stream>>>(
        idx4, n4, h, Wih, bih, Whh, bhh, hk + (size_t)n1 * 64);
    mlp_out_fb<<<blocksN1, 256, 0, stream>>>(h, hk, n1, W1, b1, W2, b2, out);
}

// Round 11
// 2306.650 us; speedup vs baseline: 9.1357x; 4.5869x over previous
//
#include <hip/hip_runtime.h>
#include <hip/hip_bf16.h>

__device__ __forceinline__ float sigmoidf_(float x) {
    return 1.0f / (1.0f + __expf(-x));
}
__device__ __forceinline__ float tanhf_(float x) {
    float e = __expf(2.0f * x);
    return 1.0f - 2.0f / (e + 1.0f);
}

#define FMA4(acc, a, b) \
    acc.x = fmaf(a.x, b.x, acc.x); acc.y = fmaf(a.y, b.y, acc.y); \
    acc.z = fmaf(a.z, b.z, acc.z); acc.w = fmaf(a.w, b.w, acc.w);
#define HS(v) (((v).x + (v).y) + ((v).z + (v).w))

// ---------------------------------------------------------------------------
// h0[node] = GRU step with hprev=0 (gh = bhh). Wih staged in LDS.
// ---------------------------------------------------------------------------
__global__ __launch_bounds__(256) void compute_h0(
    const float* __restrict__ h, const float* __restrict__ Wih,
    const float* __restrict__ bih, const float* __restrict__ bhh,
    float* __restrict__ h0, int n1)
{
    __shared__ float sW[3072];
    __shared__ float sB[192];
    {
        const float4* a4 = (const float4*)Wih;
        float4* sa = (float4*)sW;
#pragma unroll
        for (int c = 0; c < 3; ++c)
            sa[c * 256 + threadIdx.x] = a4[c * 256 + threadIdx.x];
        if (threadIdx.x < 192)
            sB[threadIdx.x] = (threadIdx.x < 96) ? bih[threadIdx.x]
                                                 : bhh[threadIdx.x - 96];
    }
    __syncthreads();

    int node = blockIdx.x * 256 + threadIdx.x;
    if (node >= n1) return;
    float x[32];
    const float4* hx = (const float4*)(h + (size_t)node * 32);
#pragma unroll
    for (int c = 0; c < 8; ++c) {
        float4 v = hx[c];
        x[c*4+0] = v.x; x[c*4+1] = v.y; x[c*4+2] = v.z; x[c*4+3] = v.w;
    }
    float o[32];
#pragma unroll
    for (int j = 0; j < 32; ++j) {
        float ir = sB[j], iz = sB[32 + j], in_ = sB[64 + j];
        const float4* wr = (const float4*)(sW + j * 32);
        const float4* wz = (const float4*)(sW + (32 + j) * 32);
        const float4* wn = (const float4*)(sW + (64 + j) * 32);
#pragma unroll
        for (int c = 0; c < 8; ++c) {
            float4 a = wr[c], b = wz[c], d = wn[c];
            ir  += x[c*4+0]*a.x + x[c*4+1]*a.y + x[c*4+2]*a.z + x[c*4+3]*a.w;
            iz  += x[c*4+0]*b.x + x[c*4+1]*b.y + x[c*4+2]*b.z + x[c*4+3]*b.w;
            in_ += x[c*4+0]*d.x + x[c*4+1]*d.y + x[c*4+2]*d.z + x[c*4+3]*d.w;
        }
        float r = sigmoidf_(ir + sB[96 + j]);
        float z = sigmoidf_(iz + sB[128 + j]);
        float n = tanhf_(in_ + r * sB[160 + j]);
        o[j] = (1.0f - z) * n;
    }
    float4* dst = (float4*)(h0 + (size_t)node * 32);
#pragma unroll
    for (int c = 0; c < 8; ++c)
        dst[c] = make_float4(o[c*4+0], o[c*4+1], o[c*4+2], o[c*4+3]);
}

// ---------------------------------------------------------------------------
// Batched histogram per k-list
// ---------------------------------------------------------------------------
template <int K>
__global__ __launch_bounds__(256) void hist_all(
    const int* __restrict__ idx, int nI, int* __restrict__ cnt0,
    int* __restrict__ counts, int n1)
{
    int i = blockIdx.x * 256 + threadIdx.x;
    if (i >= nI) return;
    int t = i % K;
    int node = idx[i];
    if (t == 0) atomicAdd(&cnt0[node], 1);
    else        atomicAdd(&counts[(size_t)(t - 1) * n1 + node], 1);
}

// ---------------------------------------------------------------------------
// Scan machinery (3-level)
// ---------------------------------------------------------------------------
__global__ __launch_bounds__(256) void scan_block(
    const int* __restrict__ in, int* __restrict__ incl,
    int* __restrict__ bsums, int n)
{
    __shared__ int s[256];
    int i = blockIdx.x * 256 + threadIdx.x;
    int v = (i < n) ? in[i] : 0;
    s[threadIdx.x] = v;
    __syncthreads();
    for (int d = 1; d < 256; d <<= 1) {
        int tt = (threadIdx.x >= d) ? s[threadIdx.x - d] : 0;
        __syncthreads();
        s[threadIdx.x] += tt;
        __syncthreads();
    }
    if (i < n) incl[i] = s[threadIdx.x];
    if (threadIdx.x == 255) bsums[blockIdx.x] = s[255];
}

__global__ __launch_bounds__(1024) void scan_bsums(int* bsums, int nb)
{
    __shared__ int s[1024];
    int v = (threadIdx.x < nb) ? bsums[threadIdx.x] : 0;
    s[threadIdx.x] = v;
    __syncthreads();
    for (int d = 1; d < 1024; d <<= 1) {
        int tt = (threadIdx.x >= d) ? s[threadIdx.x - d] : 0;
        __syncthreads();
        s[threadIdx.x] += tt;
        __syncthreads();
    }
    if (threadIdx.x < nb) bsums[threadIdx.x] = s[threadIdx.x] - v; // exclusive
}

__global__ __launch_bounds__(256) void finalize_joint(
    int* __restrict__ offs, const int* __restrict__ counts,
    const int* __restrict__ bsums0, const int* __restrict__ incl1,
    const int* __restrict__ bsums1ex, int M)
{
    int i = blockIdx.x * 256 + threadIdx.x;
    if (i >= M) return;
    int b0 = i >> 8, b1 = b0 >> 8;
    offs[i] = offs[i] - counts[i] + (incl1[b0] - bsums0[b0]) + bsums1ex[b1];
}

template <int K>
__global__ __launch_bounds__(256) void fill_all(
    const int* __restrict__ idx, int nW,
    int* __restrict__ cursor, int* __restrict__ ent, int n1)
{
    int i = blockIdx.x * 256 + threadIdx.x;
    if (i >= nW) return;
    int e = i / (K - 1), tt = i % (K - 1);
    int node = idx[(size_t)e * K + tt + 1];
    int p = atomicAdd(&cursor[(size_t)tt * n1 + node], 1);
    ent[p] = e;
}

// ---------------------------------------------------------------------------
// One GRU step (t = T >= 1). ONE WAVE PER EDGE; weights distributed across
// lanes in REGISTERS: lane (j=lane&31, half=lane>>5) holds the 16-float
// half-rows of all 6 gate matrices for output j (96 VGPRs), loaded once per
// wave. Per edge: 8 global half-row loads (L1 broadcast), 96 reg-reg FMAs,
// 4 cross-half shuffle reductions, gates, coalesced 128B store. No LDS.
// ---------------------------------------------------------------------------
template <int K, int T>
__global__ __launch_bounds__(256) void gru_step_w(
    const int* __restrict__ idx, int nE, int totalWaves,
    const float* __restrict__ h, const float* __restrict__ h0,
    const float* __restrict__ Wih, const float* __restrict__ bih,
    const float* __restrict__ Whh, const float* __restrict__ bhh,
    float* __restrict__ hstate)
{
    const int lane = threadIdx.x & 63;
    const int j    = lane & 31;
    const int half = lane >> 5;
    const int wave = (blockIdx.x * 256 + threadIdx.x) >> 6;
    const float4 z4 = make_float4(0.f, 0.f, 0.f, 0.f);

    // per-lane weight half-rows (row stride of gate blocks = 32*32 = 1024)
    float4 Wir[4], Wiz[4], Win[4], Uhr[4], Uhz[4], Uhn[4];
    {
        const float* ib = Wih + (size_t)j * 32 + half * 16;
        const float* ub = Whh + (size_t)j * 32 + half * 16;
#pragma unroll
        for (int c = 0; c < 4; ++c) {
            Wir[c] = *(const float4*)(ib + c * 4);
            Wiz[c] = *(const float4*)(ib + 1024 + c * 4);
            Win[c] = *(const float4*)(ib + 2048 + c * 4);
            Uhr[c] = *(const float4*)(ub + c * 4);
            Uhz[c] = *(const float4*)(ub + 1024 + c * 4);
            Uhn[c] = *(const float4*)(ub + 2048 + c * 4);
        }
    }
    const float bsum_r = bih[j] + bhh[j];
    const float bsum_z = bih[32 + j] + bhh[32 + j];
    const float b_in   = bih[64 + j];
    const float b_hn   = bhh[64 + j];

    for (int e = wave; e < nE; e += totalWaves) {
        float4 HV[4];
        float hvj;
        if (T == 1) {
            int np = idx[(size_t)e * K];
            const float* hp = h0 + (size_t)np * 32;
            const float4* p = (const float4*)(hp + half * 16);
#pragma unroll
            for (int c = 0; c < 4; ++c) HV[c] = p[c];
            hvj = hp[j];
        } else {
            const float* hp = hstate + (size_t)e * 32;
            const float4* p = (const float4*)(hp + half * 16);
#pragma unroll
            for (int c = 0; c < 4; ++c) HV[c] = p[c];
            hvj = hp[j];
        }
        int node = idx[(size_t)e * K + T];
        float4 X[4];
        {
            const float4* p = (const float4*)(h + (size_t)node * 32 + half * 16);
#pragma unroll
            for (int c = 0; c < 4; ++c) X[c] = p[c];
        }

        float4 pr = z4, pz = z4, pin = z4, phn = z4;
#pragma unroll
        for (int c = 0; c < 4; ++c) {
            FMA4(pr, X[c], Wir[c])
            FMA4(pr, HV[c], Uhr[c])
            FMA4(pz, X[c], Wiz[c])
            FMA4(pz, HV[c], Uhz[c])
            FMA4(pin, X[c], Win[c])
            FMA4(phn, HV[c], Uhn[c])
        }
        float s_r  = HS(pr);
        float s_z  = HS(pz);
        float s_in = HS(pin);
        float s_hn = HS(phn);
        s_r  += __shfl_xor(s_r, 32);
        s_z  += __shfl_xor(s_z, 32);
        s_in += __shfl_xor(s_in, 32);
        s_hn += __shfl_xor(s_hn, 32);

        float r = sigmoidf_(s_r + bsum_r);
        float z = sigmoidf_(s_z + bsum_z);
        float n = tanhf_((s_in + b_in) + r * (s_hn + b_hn));
        float ht = (1.0f - z) * n + z * hvj;
        if (half == 0) hstate[(size_t)e * 32 + j] = ht;
    }
}

// ---------------------------------------------------------------------------
// hkk[node] = cnt0[node] * h0[node]
// ---------------------------------------------------------------------------
__global__ __launch_bounds__(256) void init_hkk(
    const int* __restrict__ cnt0, const float* __restrict__ h0,
    float* __restrict__ hkk, int n1)
{
    int gid = blockIdx.x * 256 + threadIdx.x;
    int node = gid >> 3;
    int sub = gid & 7;
    if (node >= n1) return;
    float c = (float)cnt0[node];
    float4 v = *(const float4*)(h0 + (size_t)node * 32 + sub * 4);
    v.x *= c; v.y *= c; v.z *= c; v.w *= c;
    *(float4*)(hkk + (size_t)node * 32 + sub * 4) = v;
}

// ---------------------------------------------------------------------------
// hkk[node] += sum over entries of hstate rows. 8 threads/node, no atomics.
// ---------------------------------------------------------------------------
__global__ __launch_bounds__(256) void gather_add(
    const int* __restrict__ offs, const int* __restrict__ endp,
    const int* __restrict__ ent,
    const float* __restrict__ hstate, float* __restrict__ hkk, int n1)
{
    int gid = blockIdx.x * 256 + threadIdx.x;
    int node = gid >> 3;
    int sub = gid & 7;
    if (node >= n1) return;
    int beg = offs[node], end = endp[node];
    if (beg == end) return;
    float4 a = make_float4(0.f, 0.f, 0.f, 0.f);
    for (int p = beg; p < end; ++p) {
        int e = ent[p];
        float4 v = *(const float4*)(hstate + (size_t)e * 32 + sub * 4);
        a.x += v.x; a.y += v.y; a.z += v.z; a.w += v.w;
    }
    float* dst = hkk + (size_t)node * 32 + sub * 4;
    float4 cur = *(float4*)dst;
    cur.x += a.x; cur.y += a.y; cur.z += a.z; cur.w += a.w;
    *(float4*)dst = cur;
}

// ---------------------------------------------------------------------------
// acc(=out)[node] = b1 + h[node] @ W1[:,0:32].T
// ---------------------------------------------------------------------------
__global__ __launch_bounds__(256) void init_acc(
    const float* __restrict__ h, const float* __restrict__ W1,
    const float* __restrict__ b1, float* __restrict__ acc, int n1)
{
    __shared__ float sW[1024];
#pragma unroll
    for (int c = 0; c < 4; ++c) {
        int i = c * 256 + threadIdx.x;
        sW[i] = W1[(i >> 5) * 128 + (i & 31)];
    }
    __syncthreads();

    int node = blockIdx.x * 256 + threadIdx.x;
    if (node >= n1) return;
    float x[32];
    const float4* hx = (const float4*)(h + (size_t)node * 32);
#pragma unroll
    for (int c = 0; c < 8; ++c) {
        float4 v = hx[c];
        x[c*4+0] = v.x; x[c*4+1] = v.y; x[c*4+2] = v.z; x[c*4+3] = v.w;
    }
    float* arow = acc + (size_t)node * 32;
#pragma unroll
    for (int jb = 0; jb < 8; ++jb) {
        float o[4];
#pragma unroll
        for (int q = 0; q < 4; ++q) {
            int j = jb * 4 + q;
            float a = b1[j];
            const float4* w4 = (const float4*)(sW + j * 32);
#pragma unroll
            for (int c = 0; c < 8; ++c) {
                float4 w = w4[c];
                a += x[c*4+0]*w.x + x[c*4+1]*w.y + x[c*4+2]*w.z + x[c*4+3]*w.w;
            }
            o[q] = a;
        }
        *(float4*)(arow + jb * 4) = make_float4(o[0], o[1], o[2], o[3]);
    }
}

// ---------------------------------------------------------------------------
// acc(=out)[node] += hkk[node] @ W1blk.T
// ---------------------------------------------------------------------------
__global__ __launch_bounds__(256) void fold_w1(
    const float* __restrict__ hkk, const float* __restrict__ W1blk,
    float* __restrict__ acc, int n1)
{
    __shared__ float sW[1024];
#pragma unroll
    for (int c = 0; c < 4; ++c) {
        int i = c * 256 + threadIdx.x;
        sW[i] = W1blk[(i >> 5) * 128 + (i & 31)];
    }
    __syncthreads();

    int node = blockIdx.x * 256 + threadIdx.x;
    if (node >= n1) return;
    float x[32];
    const float4* hx = (const float4*)(hkk + (size_t)node * 32);
#pragma unroll
    for (int c = 0; c < 8; ++c) {
        float4 v = hx[c];
        x[c*4+0] = v.x; x[c*4+1] = v.y; x[c*4+2] = v.z; x[c*4+3] = v.w;
    }
    float* arow = acc + (size_t)node * 32;
#pragma unroll
    for (int jb = 0; jb < 8; ++jb) {
        float4 cur = *(float4*)(arow + jb * 4);
        float o[4] = { cur.x, cur.y, cur.z, cur.w };
#pragma unroll
        for (int q = 0; q < 4; ++q) {
            int j = jb * 4 + q;
            float a = o[q];
            const float4* w4 = (const float4*)(sW + j * 32);
#pragma unroll
            for (int c = 0; c < 8; ++c) {
                float4 w = w4[c];
                a += x[c*4+0]*w.x + x[c*4+1]*w.y + x[c*4+2]*w.z + x[c*4+3]*w.w;
            }
            o[q] = a;
        }
        *(float4*)(arow + jb * 4) = make_float4(o[0], o[1], o[2], o[3]);
    }
}

// ---------------------------------------------------------------------------
// out[node] = tanh(acc[node]) @ W2.T + b2   (in-place)
// ---------------------------------------------------------------------------
__global__ __launch_bounds__(256) void finish_out(
    float* __restrict__ acc, const float* __restrict__ W2,
    const float* __restrict__ b2, int n1)
{
    __shared__ float sW[1024];
    {
        const float4* w4 = (const float4*)W2;
        float4* s4 = (float4*)sW;
        if (threadIdx.x < 256) s4[threadIdx.x] = w4[threadIdx.x];
    }
    __syncthreads();

    int node = blockIdx.x * 256 + threadIdx.x;
    if (node >= n1) return;
    float tv[32];
    const float4* ax = (const float4*)(acc + (size_t)node * 32);
#pragma unroll
    for (int c = 0; c < 8; ++c) {
        float4 v = ax[c];
        tv[c*4+0] = tanhf_(v.x); tv[c*4+1] = tanhf_(v.y);
        tv[c*4+2] = tanhf_(v.z); tv[c*4+3] = tanhf_(v.w);
    }
    float* orow = acc + (size_t)node * 32;
#pragma unroll
    for (int ob = 0; ob < 8; ++ob) {
        float o[4];
#pragma unroll
        for (int q = 0; q < 4; ++q) {
            int oj = ob * 4 + q;
            float a = b2[oj];
            const float4* w4 = (const float4*)(sW + oj * 32);
#pragma unroll
            for (int c = 0; c < 8; ++c) {
                float4 w = w4[c];
                a += tv[c*4+0]*w.x + tv[c*4+1]*w.y + tv[c*4+2]*w.z + tv[c*4+3]*w.w;
            }
            o[q] = a;
        }
        *(float4*)(orow + ob * 4) = make_float4(o[0], o[1], o[2], o[3]);
    }
}

// ---------------------------------------------------------------------------
// Fallback: atomic scatter (slow, correct)
// ---------------------------------------------------------------------------
template <int K>
__global__ __launch_bounds__(256) void gru_edges_atomic_noG(
    const int* __restrict__ idx, int nE,
    const float* __restrict__ h,
    const float* __restrict__ Wih, const float* __restrict__ bih,
    const float* __restrict__ Whh, const float* __restrict__ bhh,
    float* __restrict__ hk)
{
    int e = blockIdx.x * 256 + threadIdx.x;
    if (e >= nE) return;
    float hv[32];
#pragma unroll
    for (int t = 0; t < K; ++t) {
        int node = idx[(size_t)e * K + t];
        float x[32];
        const float4* hx = (const float4*)(h + (size_t)node * 32);
#pragma unroll
        for (int c = 0; c < 8; ++c) {
            float4 v = hx[c];
            x[c*4+0] = v.x; x[c*4+1] = v.y; x[c*4+2] = v.z; x[c*4+3] = v.w;
        }
        float hn_[32];
#pragma unroll
        for (int j = 0; j < 32; ++j) {
            float ir = bih[j], iz = bih[32 + j], in_ = bih[64 + j];
#pragma unroll
            for (int i = 0; i < 32; ++i) {
                ir  += x[i] * Wih[j * 32 + i];
                iz  += x[i] * Wih[(32 + j) * 32 + i];
                in_ += x[i] * Wih[(64 + j) * 32 + i];
            }
            float hr = bhh[j], hz = bhh[32 + j], hn2 = bhh[64 + j];
            if (t > 0) {
#pragma unroll
                for (int i = 0; i < 32; ++i) {
                    hr  += hv[i] * Whh[j * 32 + i];
                    hz  += hv[i] * Whh[(32 + j) * 32 + i];
                    hn2 += hv[i] * Whh[(64 + j) * 32 + i];
                }
            }
            float r = sigmoidf_(ir + hr);
            float z = sigmoidf_(iz + hz);
            float n = tanhf_(in_ + r * hn2);
            hn_[j] = (t > 0) ? ((1.0f - z) * n + z * hv[j]) : (1.0f - z) * n;
        }
        float* dst = hk + (size_t)node * 32;
#pragma unroll
        for (int j = 0; j < 32; ++j) {
            hv[j] = hn_[j];
            atomicAdd(dst + j, hn_[j]);
        }
    }
}

__global__ __launch_bounds__(256) void mlp_out_fb(
    const float* __restrict__ h, const float* __restrict__ hk, int n1,
    const float* __restrict__ W1, const float* __restrict__ b1,
    const float* __restrict__ W2, const float* __restrict__ b2,
    float* __restrict__ out)
{
    int node = blockIdx.x * 256 + threadIdx.x;
    if (node >= n1) return;
    float acc[32];
#pragma unroll
    for (int j = 0; j < 32; ++j) acc[j] = b1[j];
    const float* zsrc[4];
    zsrc[0] = h + (size_t)node * 32;
    zsrc[1] = hk + (size_t)node * 32;
    zsrc[2] = hk + (size_t)n1 * 32 + (size_t)node * 32;
    zsrc[3] = hk + (size_t)n1 * 64 + (size_t)node * 32;
#pragma unroll
    for (int m = 0; m < 4; ++m) {
        float zc[32];
        const float4* zp = (const float4*)zsrc[m];
#pragma unroll
        for (int c = 0; c < 8; ++c) {
            float4 v = zp[c];
            zc[c*4+0] = v.x; zc[c*4+1] = v.y; zc[c*4+2] = v.z; zc[c*4+3] = v.w;
        }
#pragma unroll
        for (int j = 0; j < 32; ++j) {
#pragma unroll
            for (int i = 0; i < 32; ++i)
                acc[j] += zc[i] * W1[j * 128 + m * 32 + i];
        }
    }
    float tv[32];
#pragma unroll
    for (int j = 0; j < 32; ++j) tv[j] = tanhf_(acc[j]);
    float* orow = out + (size_t)node * 32;
#pragma unroll
    for (int ob = 0; ob < 8; ++ob) {
        float o[4];
#pragma unroll
        for (int q = 0; q < 4; ++q) {
            int oj = ob * 4 + q;
            float a = b2[oj];
#pragma unroll
            for (int j = 0; j < 32; ++j)
                a += tv[j] * W2[oj * 32 + j];
            o[q] = a;
        }
        *(float4*)(orow + ob * 4) = make_float4(o[0], o[1], o[2], o[3]);
    }
}

// ---------------------------------------------------------------------------
static inline size_t alignUp(size_t x, size_t a) { return (x + a - 1) & ~(a - 1); }

extern "C" void kernel_launch(void* const* d_in, const int* in_sizes, int n_in,
                              void* d_out, int out_size, void* d_ws, size_t ws_size,
                              hipStream_t stream)
{
    const float* h    = (const float*)d_in[0];
    const int*   idx2 = (const int*)d_in[1];
    const int*   idx3 = (const int*)d_in[2];
    const int*   idx4 = (const int*)d_in[3];
    const float* Wih  = (const float*)d_in[4];
    const float* Whh  = (const float*)d_in[5];
    const float* bih  = (const float*)d_in[6];
    const float* bhh  = (const float*)d_in[7];
    const float* W1   = (const float*)d_in[8];
    const float* b1   = (const float*)d_in[9];
    const float* W2   = (const float*)d_in[10];
    const float* b2   = (const float*)d_in[11];
    float* out = (float*)d_out;

    int n1 = in_sizes[0] / 32;
    int n2 = in_sizes[1] / 2;
    int n3 = in_sizes[2] / 3;
    int n4 = in_sizes[3] / 4;
    int nEmax = n2 > n3 ? n2 : n3; if (n4 > nEmax) nEmax = n4;

    const int NCOL = 6;
    int M = NCOL * n1;
    int B0 = (M + 255) / 256;
    int B1 = (B0 + 255) / 256;
    size_t totE = (size_t)n2 + 2 * (size_t)n3 + 3 * (size_t)n4;

    // ---- workspace layout ----
    size_t off = 0;
    size_t h0Off  = off; off = alignUp(off + (size_t)n1 * 32 * 4, 256);
    size_t hsOff  = off; off = alignUp(off + (size_t)nEmax * 32 * 4, 256);
    size_t hkkOff = off; off = alignUp(off + (size_t)n1 * 32 * 4, 256);
    size_t cntOff = off; off = alignUp(off + (size_t)M * 4, 256);
    size_t c0Off  = off; off = alignUp(off + (size_t)3 * n1 * 4, 256);
    size_t oOff   = off; off = alignUp(off + (size_t)M * 4, 256);
    size_t entOff = off; off = alignUp(off + totE * 4, 256);
    size_t b0Off  = off; off = alignUp(off + (size_t)B0 * 4, 256);
    size_t i1Off  = off; off = alignUp(off + (size_t)B0 * 4, 256);
    size_t b1Off  = off; off = alignUp(off + (size_t)B1 * 4, 256);
    size_t need = off;

    int blocksN1 = (n1 + 255) / 256;
    char* ws = (char*)d_ws;

    if (ws_size >= need && B1 <= 1024) {
        float* h0     = (float*)(ws + h0Off);
        float* hstate = (float*)(ws + hsOff);
        float* hkk    = (float*)(ws + hkkOff);
        int*   counts = (int*)(ws + cntOff);
        int*   cnt0   = (int*)(ws + c0Off);
        int*   offs   = (int*)(ws + oOff);
        int*   ent    = (int*)(ws + entOff);
        int*   bsums0 = (int*)(ws + b0Off);
        int*   incl1  = (int*)(ws + i1Off);
        int*   bsums1 = (int*)(ws + b1Off);

        // --- CSR build ---
        hipMemsetAsync(counts, 0, ((size_t)M + 3 * n1) * 4, stream);
        hist_all<2><<<(n2 * 2 + 255) / 256, 256, 0, stream>>>(idx2, n2 * 2, cnt0,          counts,          n1);
        hist_all<3><<<(n3 * 3 + 255) / 256, 256, 0, stream>>>(idx3, n3 * 3, cnt0 + n1,     counts + n1,     n1);
        hist_all<4><<<(n4 * 4 + 255) / 256, 256, 0, stream>>>(idx4, n4 * 4, cnt0 + 2 * n1, counts + 3 * n1, n1);
        scan_block<<<B0, 256, 0, stream>>>(counts, offs, bsums0, M);
        scan_block<<<B1, 256, 0, stream>>>(bsums0, incl1, bsums1, B0);
        scan_bsums<<<1, 1024, 0, stream>>>(bsums1, B1);
        finalize_joint<<<B0, 256, 0, stream>>>(offs, counts, bsums0, incl1, bsums1, M);
        hipMemcpyAsync(counts, offs, (size_t)M * 4, hipMemcpyDeviceToDevice, stream);
        fill_all<2><<<(n2 * 1 + 255) / 256, 256, 0, stream>>>(idx2, n2 * 1, counts,          ent, n1);
        fill_all<3><<<(n3 * 2 + 255) / 256, 256, 0, stream>>>(idx3, n3 * 2, counts + n1,     ent, n1);
        fill_all<4><<<(n4 * 3 + 255) / 256, 256, 0, stream>>>(idx4, n4 * 3, counts + 3 * n1, ent, n1);

        // --- node-side precomputes ---
        compute_h0<<<blocksN1, 256, 0, stream>>>(h, Wih, bih, bhh, h0, n1);
        init_acc<<<blocksN1, 256, 0, stream>>>(h, W1, b1, out, n1);

        // --- per-k pipeline ---
        const int* idxs[3] = { idx2, idx3, idx4 };
        int nEs[3] = { n2, n3, n4 };
        int colbase[3] = { 0, 1, 3 };
        int gaBlocks = ((n1 * 8) + 255) / 256;
        const int gwBlocks = 1024;                 // 4096 waves
        const int totalWaves = gwBlocks * 4;

        for (int kk = 0; kk < 3; ++kk) {
            const int* idx = idxs[kk];
            int nE = nEs[kk];

            init_hkk<<<gaBlocks, 256, 0, stream>>>(cnt0 + kk * n1, h0, hkk, n1);

            int K = kk + 2;
            for (int t = 1; t < K; ++t) {
                if (K == 2)      gru_step_w<2, 1><<<gwBlocks, 256, 0, stream>>>(idx, nE, totalWaves, h, h0, Wih, bih, Whh, bhh, hstate);
                else if (K == 3) {
                    if (t == 1)  gru_step_w<3, 1><<<gwBlocks, 256, 0, stream>>>(idx, nE, totalWaves, h, h0, Wih, bih, Whh, bhh, hstate);
                    else         gru_step_w<3, 2><<<gwBlocks, 256, 0, stream>>>(idx, nE, totalWaves, h, h0, Wih, bih, Whh, bhh, hstate);
                } else {
                    if (t == 1)      gru_step_w<4, 1><<<gwBlocks, 256, 0, stream>>>(idx, nE, totalWaves, h, h0, Wih, bih, Whh, bhh, hstate);
                    else if (t == 2) gru_step_w<4, 2><<<gwBlocks, 256, 0, stream>>>(idx, nE, totalWaves, h, h0, Wih, bih, Whh, bhh, hstate);
                    else             gru_step_w<4, 3><<<gwBlocks, 256, 0, stream>>>(idx, nE, totalWaves, h, h0, Wih, bih, Whh, bhh, hstate);
                }
                int col = colbase[kk] + (t - 1);
                gather_add<<<gaBlocks, 256, 0, stream>>>(
                    offs + (size_t)col * n1, counts + (size_t)col * n1,
                    ent, hstate, hkk, n1);
            }

            fold_w1<<<blocksN1, 256, 0, stream>>>(hkk, W1 + (kk + 1) * 32, out, n1);
        }

        finish_out<<<blocksN1, 256, 0, stream>>>(out, W2, b2, n1);
        return;
    }

    // ===== fallback: atomic path =====
    float* hk = (float*)d_ws;
    hipMemsetAsync(d_ws, 0, (size_t)n1 * 96 * 4, stream);
    gru_edges_atomic_noG<2><<<(n2 + 255) / 256, 256, 0, stream>>>(
        idx2, n2, h, Wih, bih, Whh, bhh, hk);
    gru_edges_atomic_noG<3><<<(n3 + 255) / 256, 256, 0, stream>>>(
        idx3, n3, h, Wih, bih, Whh, bhh, hk + (size_t)n1 * 32);
    gru_edges_atomic_noG<4><<<(n4 + 255) / 256, 256, 0, stream>>>(
        idx4, n4, h, Wih, bih, Whh, bhh, hk + (size_t)n1 * 64);
    mlp_out_fb<<<blocksN1, 256, 0, stream>>>(h, hk, n1, W1, b1, W2, b2, out);
}

// Round 12
// 1955.032 us; speedup vs baseline: 10.7788x; 1.1799x over previous
//
#include <hip/hip_runtime.h>
#include <hip/hip_bf16.h>

__device__ __forceinline__ float sigmoidf_(float x) {
    return 1.0f / (1.0f + __expf(-x));
}
__device__ __forceinline__ float tanhf_(float x) {
    float e = __expf(2.0f * x);
    return 1.0f - 2.0f / (e + 1.0f);
}

#define FMA4(acc, a, b) \
    acc.x = fmaf(a.x, b.x, acc.x); acc.y = fmaf(a.y, b.y, acc.y); \
    acc.z = fmaf(a.z, b.z, acc.z); acc.w = fmaf(a.w, b.w, acc.w);
#define HS(v) (((v).x + (v).y) + ((v).z + (v).w))

// ---------------------------------------------------------------------------
// h0[node] = GRU step with hprev=0 (gh = bhh). Wih staged in LDS.
// ---------------------------------------------------------------------------
__global__ __launch_bounds__(256) void compute_h0(
    const float* __restrict__ h, const float* __restrict__ Wih,
    const float* __restrict__ bih, const float* __restrict__ bhh,
    float* __restrict__ h0, int n1)
{
    __shared__ float sW[3072];
    __shared__ float sB[192];
    {
        const float4* a4 = (const float4*)Wih;
        float4* sa = (float4*)sW;
#pragma unroll
        for (int c = 0; c < 3; ++c)
            sa[c * 256 + threadIdx.x] = a4[c * 256 + threadIdx.x];
        if (threadIdx.x < 192)
            sB[threadIdx.x] = (threadIdx.x < 96) ? bih[threadIdx.x]
                                                 : bhh[threadIdx.x - 96];
    }
    __syncthreads();

    int node = blockIdx.x * 256 + threadIdx.x;
    if (node >= n1) return;
    float x[32];
    const float4* hx = (const float4*)(h + (size_t)node * 32);
#pragma unroll
    for (int c = 0; c < 8; ++c) {
        float4 v = hx[c];
        x[c*4+0] = v.x; x[c*4+1] = v.y; x[c*4+2] = v.z; x[c*4+3] = v.w;
    }
    float o[32];
#pragma unroll
    for (int j = 0; j < 32; ++j) {
        float ir = sB[j], iz = sB[32 + j], in_ = sB[64 + j];
        const float4* wr = (const float4*)(sW + j * 32);
        const float4* wz = (const float4*)(sW + (32 + j) * 32);
        const float4* wn = (const float4*)(sW + (64 + j) * 32);
#pragma unroll
        for (int c = 0; c < 8; ++c) {
            float4 a = wr[c], b = wz[c], d = wn[c];
            ir  += x[c*4+0]*a.x + x[c*4+1]*a.y + x[c*4+2]*a.z + x[c*4+3]*a.w;
            iz  += x[c*4+0]*b.x + x[c*4+1]*b.y + x[c*4+2]*b.z + x[c*4+3]*b.w;
            in_ += x[c*4+0]*d.x + x[c*4+1]*d.y + x[c*4+2]*d.z + x[c*4+3]*d.w;
        }
        float r = sigmoidf_(ir + sB[96 + j]);
        float z = sigmoidf_(iz + sB[128 + j]);
        float n = tanhf_(in_ + r * sB[160 + j]);
        o[j] = (1.0f - z) * n;
    }
    float4* dst = (float4*)(h0 + (size_t)node * 32);
#pragma unroll
    for (int c = 0; c < 8; ++c)
        dst[c] = make_float4(o[c*4+0], o[c*4+1], o[c*4+2], o[c*4+3]);
}

// ---------------------------------------------------------------------------
// Batched histogram per k-list
// ---------------------------------------------------------------------------
template <int K>
__global__ __launch_bounds__(256) void hist_all(
    const int* __restrict__ idx, int nI, int* __restrict__ cnt0,
    int* __restrict__ counts, int n1)
{
    int i = blockIdx.x * 256 + threadIdx.x;
    if (i >= nI) return;
    int t = i % K;
    int node = idx[i];
    if (t == 0) atomicAdd(&cnt0[node], 1);
    else        atomicAdd(&counts[(size_t)(t - 1) * n1 + node], 1);
}

// ---------------------------------------------------------------------------
// Scan machinery (3-level)
// ---------------------------------------------------------------------------
__global__ __launch_bounds__(256) void scan_block(
    const int* __restrict__ in, int* __restrict__ incl,
    int* __restrict__ bsums, int n)
{
    __shared__ int s[256];
    int i = blockIdx.x * 256 + threadIdx.x;
    int v = (i < n) ? in[i] : 0;
    s[threadIdx.x] = v;
    __syncthreads();
    for (int d = 1; d < 256; d <<= 1) {
        int tt = (threadIdx.x >= d) ? s[threadIdx.x - d] : 0;
        __syncthreads();
        s[threadIdx.x] += tt;
        __syncthreads();
    }
    if (i < n) incl[i] = s[threadIdx.x];
    if (threadIdx.x == 255) bsums[blockIdx.x] = s[255];
}

__global__ __launch_bounds__(1024) void scan_bsums(int* bsums, int nb)
{
    __shared__ int s[1024];
    int v = (threadIdx.x < nb) ? bsums[threadIdx.x] : 0;
    s[threadIdx.x] = v;
    __syncthreads();
    for (int d = 1; d < 1024; d <<= 1) {
        int tt = (threadIdx.x >= d) ? s[threadIdx.x - d] : 0;
        __syncthreads();
        s[threadIdx.x] += tt;
        __syncthreads();
    }
    if (threadIdx.x < nb) bsums[threadIdx.x] = s[threadIdx.x] - v; // exclusive
}

__global__ __launch_bounds__(256) void finalize_joint(
    int* __restrict__ offs, const int* __restrict__ counts,
    const int* __restrict__ bsums0, const int* __restrict__ incl1,
    const int* __restrict__ bsums1ex, int M)
{
    int i = blockIdx.x * 256 + threadIdx.x;
    if (i >= M) return;
    int b0 = i >> 8, b1 = b0 >> 8;
    offs[i] = offs[i] - counts[i] + (incl1[b0] - bsums0[b0]) + bsums1ex[b1];
}

template <int K>
__global__ __launch_bounds__(256) void fill_all(
    const int* __restrict__ idx, int nW,
    int* __restrict__ cursor, int* __restrict__ ent, int n1)
{
    int i = blockIdx.x * 256 + threadIdx.x;
    if (i >= nW) return;
    int e = i / (K - 1), tt = i % (K - 1);
    int node = idx[(size_t)e * K + tt + 1];
    int p = atomicAdd(&cursor[(size_t)tt * n1 + node], 1);
    ent[p] = e;
}

// ---------------------------------------------------------------------------
// One GRU step (t = T >= 1). ONE WAVE PER EDGE; weights live in registers
// distributed across lanes (lane j=lane&31, half=lane>>5 holds the 16-float
// half-rows of all 6 gate matrices for output j). Next-iteration indices are
// prefetched so the idx-load latency hides under the 96 FMAs.
// ---------------------------------------------------------------------------
template <int K, int T>
__global__ __launch_bounds__(256) void gru_step_w(
    const int* __restrict__ idx, int nE, int totalWaves,
    const float* __restrict__ h, const float* __restrict__ h0,
    const float* __restrict__ Wih, const float* __restrict__ bih,
    const float* __restrict__ Whh, const float* __restrict__ bhh,
    float* __restrict__ hstate)
{
    const int lane = threadIdx.x & 63;
    const int j    = lane & 31;
    const int half = lane >> 5;
    const int wave = (blockIdx.x * 256 + threadIdx.x) >> 6;
    const float4 z4 = make_float4(0.f, 0.f, 0.f, 0.f);

    float4 Wir[4], Wiz[4], Win[4], Uhr[4], Uhz[4], Uhn[4];
    {
        const float* ib = Wih + (size_t)j * 32 + half * 16;
        const float* ub = Whh + (size_t)j * 32 + half * 16;
#pragma unroll
        for (int c = 0; c < 4; ++c) {
            Wir[c] = *(const float4*)(ib + c * 4);
            Wiz[c] = *(const float4*)(ib + 1024 + c * 4);
            Win[c] = *(const float4*)(ib + 2048 + c * 4);
            Uhr[c] = *(const float4*)(ub + c * 4);
            Uhz[c] = *(const float4*)(ub + 1024 + c * 4);
            Uhn[c] = *(const float4*)(ub + 2048 + c * 4);
        }
    }
    const float bsum_r = bih[j] + bhh[j];
    const float bsum_z = bih[32 + j] + bhh[32 + j];
    const float b_in   = bih[64 + j];
    const float b_hn   = bhh[64 + j];

    int e = wave;
    if (e >= nE) return;
    int nodeT_c = idx[(size_t)e * K + T];
    int prev_c  = (T == 1) ? idx[(size_t)e * K] : 0;

    for (; e < nE; e += totalWaves) {
        // prefetch next iteration's indices (latency hides under FMAs)
        int en = e + totalWaves;
        int nodeT_n = 0, prev_n = 0;
        if (en < nE) {
            nodeT_n = idx[(size_t)en * K + T];
            if (T == 1) prev_n = idx[(size_t)en * K];
        }

        float4 HV[4];
        float hvj;
        if (T == 1) {
            const float* hp = h0 + (size_t)prev_c * 32;
            const float4* p = (const float4*)(hp + half * 16);
#pragma unroll
            for (int c = 0; c < 4; ++c) HV[c] = p[c];
            hvj = hp[j];
        } else {
            const float* hp = hstate + (size_t)e * 32;
            const float4* p = (const float4*)(hp + half * 16);
#pragma unroll
            for (int c = 0; c < 4; ++c) HV[c] = p[c];
            hvj = hp[j];
        }
        float4 X[4];
        {
            const float4* p = (const float4*)(h + (size_t)nodeT_c * 32 + half * 16);
#pragma unroll
            for (int c = 0; c < 4; ++c) X[c] = p[c];
        }

        float4 pr = z4, pz = z4, pin = z4, phn = z4;
#pragma unroll
        for (int c = 0; c < 4; ++c) {
            FMA4(pr, X[c], Wir[c])
            FMA4(pr, HV[c], Uhr[c])
            FMA4(pz, X[c], Wiz[c])
            FMA4(pz, HV[c], Uhz[c])
            FMA4(pin, X[c], Win[c])
            FMA4(phn, HV[c], Uhn[c])
        }
        float s_r  = HS(pr);
        float s_z  = HS(pz);
        float s_in = HS(pin);
        float s_hn = HS(phn);
        s_r  += __shfl_xor(s_r, 32);
        s_z  += __shfl_xor(s_z, 32);
        s_in += __shfl_xor(s_in, 32);
        s_hn += __shfl_xor(s_hn, 32);

        float r = sigmoidf_(s_r + bsum_r);
        float z = sigmoidf_(s_z + bsum_z);
        float n = tanhf_((s_in + b_in) + r * (s_hn + b_hn));
        float ht = (1.0f - z) * n + z * hvj;
        if (half == 0) hstate[(size_t)e * 32 + j] = ht;

        nodeT_c = nodeT_n;
        prev_c  = prev_n;
    }
}

// ---------------------------------------------------------------------------
// hkk[node] = cnt0[node] * h0[node]
// ---------------------------------------------------------------------------
__global__ __launch_bounds__(256) void init_hkk(
    const int* __restrict__ cnt0, const float* __restrict__ h0,
    float* __restrict__ hkk, int n1)
{
    int gid = blockIdx.x * 256 + threadIdx.x;
    int node = gid >> 3;
    int sub = gid & 7;
    if (node >= n1) return;
    float c = (float)cnt0[node];
    float4 v = *(const float4*)(h0 + (size_t)node * 32 + sub * 4);
    v.x *= c; v.y *= c; v.z *= c; v.w *= c;
    *(float4*)(hkk + (size_t)node * 32 + sub * 4) = v;
}

// ---------------------------------------------------------------------------
// hkk[node] += sum over entries of hstate rows. 8 threads/node, no atomics.
// ---------------------------------------------------------------------------
__global__ __launch_bounds__(256) void gather_add(
    const int* __restrict__ offs, const int* __restrict__ endp,
    const int* __restrict__ ent,
    const float* __restrict__ hstate, float* __restrict__ hkk, int n1)
{
    int gid = blockIdx.x * 256 + threadIdx.x;
    int node = gid >> 3;
    int sub = gid & 7;
    if (node >= n1) return;
    int beg = offs[node], end = endp[node];
    if (beg == end) return;
    float4 a = make_float4(0.f, 0.f, 0.f, 0.f);
    for (int p = beg; p < end; ++p) {
        int e = ent[p];
        float4 v = *(const float4*)(hstate + (size_t)e * 32 + sub * 4);
        a.x += v.x; a.y += v.y; a.z += v.z; a.w += v.w;
    }
    float* dst = hkk + (size_t)node * 32 + sub * 4;
    float4 cur = *(float4*)dst;
    cur.x += a.x; cur.y += a.y; cur.z += a.z; cur.w += a.w;
    *(float4*)dst = cur;
}

// ---------------------------------------------------------------------------
// acc(=out)[node] = b1 + h[node] @ W1[:,0:32].T
// ---------------------------------------------------------------------------
__global__ __launch_bounds__(256) void init_acc(
    const float* __restrict__ h, const float* __restrict__ W1,
    const float* __restrict__ b1, float* __restrict__ acc, int n1)
{
    __shared__ float sW[1024];
#pragma unroll
    for (int c = 0; c < 4; ++c) {
        int i = c * 256 + threadIdx.x;
        sW[i] = W1[(i >> 5) * 128 + (i & 31)];
    }
    __syncthreads();

    int node = blockIdx.x * 256 + threadIdx.x;
    if (node >= n1) return;
    float x[32];
    const float4* hx = (const float4*)(h + (size_t)node * 32);
#pragma unroll
    for (int c = 0; c < 8; ++c) {
        float4 v = hx[c];
        x[c*4+0] = v.x; x[c*4+1] = v.y; x[c*4+2] = v.z; x[c*4+3] = v.w;
    }
    float* arow = acc + (size_t)node * 32;
#pragma unroll
    for (int jb = 0; jb < 8; ++jb) {
        float o[4];
#pragma unroll
        for (int q = 0; q < 4; ++q) {
            int j = jb * 4 + q;
            float a = b1[j];
            const float4* w4 = (const float4*)(sW + j * 32);
#pragma unroll
            for (int c = 0; c < 8; ++c) {
                float4 w = w4[c];
                a += x[c*4+0]*w.x + x[c*4+1]*w.y + x[c*4+2]*w.z + x[c*4+3]*w.w;
            }
            o[q] = a;
        }
        *(float4*)(arow + jb * 4) = make_float4(o[0], o[1], o[2], o[3]);
    }
}

// ---------------------------------------------------------------------------
// acc(=out)[node] += hkk[node] @ W1blk.T
// ---------------------------------------------------------------------------
__global__ __launch_bounds__(256) void fold_w1(
    const float* __restrict__ hkk, const float* __restrict__ W1blk,
    float* __restrict__ acc, int n1)
{
    __shared__ float sW[1024];
#pragma unroll
    for (int c = 0; c < 4; ++c) {
        int i = c * 256 + threadIdx.x;
        sW[i] = W1blk[(i >> 5) * 128 + (i & 31)];
    }
    __syncthreads();

    int node = blockIdx.x * 256 + threadIdx.x;
    if (node >= n1) return;
    float x[32];
    const float4* hx = (const float4*)(hkk + (size_t)node * 32);
#pragma unroll
    for (int c = 0; c < 8; ++c) {
        float4 v = hx[c];
        x[c*4+0] = v.x; x[c*4+1] = v.y; x[c*4+2] = v.z; x[c*4+3] = v.w;
    }
    float* arow = acc + (size_t)node * 32;
#pragma unroll
    for (int jb = 0; jb < 8; ++jb) {
        float4 cur = *(float4*)(arow + jb * 4);
        float o[4] = { cur.x, cur.y, cur.z, cur.w };
#pragma unroll
        for (int q = 0; q < 4; ++q) {
            int j = jb * 4 + q;
            float a = o[q];
            const float4* w4 = (const float4*)(sW + j * 32);
#pragma unroll
            for (int c = 0; c < 8; ++c) {
                float4 w = w4[c];
                a += x[c*4+0]*w.x + x[c*4+1]*w.y + x[c*4+2]*w.z + x[c*4+3]*w.w;
            }
            o[q] = a;
        }
        *(float4*)(arow + jb * 4) = make_float4(o[0], o[1], o[2], o[3]);
    }
}

// ---------------------------------------------------------------------------
// out[node] = tanh(acc[node]) @ W2.T + b2   (in-place)
// ---------------------------------------------------------------------------
__global__ __launch_bounds__(256) void finish_out(
    float* __restrict__ acc, const float* __restrict__ W2,
    const float* __restrict__ b2, int n1)
{
    __shared__ float sW[1024];
    {
        const float4* w4 = (const float4*)W2;
        float4* s4 = (float4*)sW;
        if (threadIdx.x < 256) s4[threadIdx.x] = w4[threadIdx.x];
    }
    __syncthreads();

    int node = blockIdx.x * 256 + threadIdx.x;
    if (node >= n1) return;
    float tv[32];
    const float4* ax = (const float4*)(acc + (size_t)node * 32);
#pragma unroll
    for (int c = 0; c < 8; ++c) {
        float4 v = ax[c];
        tv[c*4+0] = tanhf_(v.x); tv[c*4+1] = tanhf_(v.y);
        tv[c*4+2] = tanhf_(v.z); tv[c*4+3] = tanhf_(v.w);
    }
    float* orow = acc + (size_t)node * 32;
#pragma unroll
    for (int ob = 0; ob < 8; ++ob) {
        float o[4];
#pragma unroll
        for (int q = 0; q < 4; ++q) {
            int oj = ob * 4 + q;
            float a = b2[oj];
            const float4* w4 = (const float4*)(sW + oj * 32);
#pragma unroll
            for (int c = 0; c < 8; ++c) {
                float4 w = w4[c];
                a += tv[c*4+0]*w.x + tv[c*4+1]*w.y + tv[c*4+2]*w.z + tv[c*4+3]*w.w;
            }
            o[q] = a;
        }
        *(float4*)(orow + ob * 4) = make_float4(o[0], o[1], o[2], o[3]);
    }
}

// ---------------------------------------------------------------------------
// Fallback: atomic scatter (slow, correct)
// ---------------------------------------------------------------------------
template <int K>
__global__ __launch_bounds__(256) void gru_edges_atomic_noG(
    const int* __restrict__ idx, int nE,
    const float* __restrict__ h,
    const float* __restrict__ Wih, const float* __restrict__ bih,
    const float* __restrict__ Whh, const float* __restrict__ bhh,
    float* __restrict__ hk)
{
    int e = blockIdx.x * 256 + threadIdx.x;
    if (e >= nE) return;
    float hv[32];
#pragma unroll
    for (int t = 0; t < K; ++t) {
        int node = idx[(size_t)e * K + t];
        float x[32];
        const float4* hx = (const float4*)(h + (size_t)node * 32);
#pragma unroll
        for (int c = 0; c < 8; ++c) {
            float4 v = hx[c];
            x[c*4+0] = v.x; x[c*4+1] = v.y; x[c*4+2] = v.z; x[c*4+3] = v.w;
        }
        float hn_[32];
#pragma unroll
        for (int j = 0; j < 32; ++j) {
            float ir = bih[j], iz = bih[32 + j], in_ = bih[64 + j];
#pragma unroll
            for (int i = 0; i < 32; ++i) {
                ir  += x[i] * Wih[j * 32 + i];
                iz  += x[i] * Wih[(32 + j) * 32 + i];
                in_ += x[i] * Wih[(64 + j) * 32 + i];
            }
            float hr = bhh[j], hz = bhh[32 + j], hn2 = bhh[64 + j];
            if (t > 0) {
#pragma unroll
                for (int i = 0; i < 32; ++i) {
                    hr  += hv[i] * Whh[j * 32 + i];
                    hz  += hv[i] * Whh[(32 + j) * 32 + i];
                    hn2 += hv[i] * Whh[(64 + j) * 32 + i];
                }
            }
            float r = sigmoidf_(ir + hr);
            float z = sigmoidf_(iz + hz);
            float n = tanhf_(in_ + r * hn2);
            hn_[j] = (t > 0) ? ((1.0f - z) * n + z * hv[j]) : (1.0f - z) * n;
        }
        float* dst = hk + (size_t)node * 32;
#pragma unroll
        for (int j = 0; j < 32; ++j) {
            hv[j] = hn_[j];
            atomicAdd(dst + j, hn_[j]);
        }
    }
}

__global__ __launch_bounds__(256) void mlp_out_fb(
    const float* __restrict__ h, const float* __restrict__ hk, int n1,
    const float* __restrict__ W1, const float* __restrict__ b1,
    const float* __restrict__ W2, const float* __restrict__ b2,
    float* __restrict__ out)
{
    int node = blockIdx.x * 256 + threadIdx.x;
    if (node >= n1) return;
    float acc[32];
#pragma unroll
    for (int j = 0; j < 32; ++j) acc[j] = b1[j];
    const float* zsrc[4];
    zsrc[0] = h + (size_t)node * 32;
    zsrc[1] = hk + (size_t)node * 32;
    zsrc[2] = hk + (size_t)n1 * 32 + (size_t)node * 32;
    zsrc[3] = hk + (size_t)n1 * 64 + (size_t)node * 32;
#pragma unroll
    for (int m = 0; m < 4; ++m) {
        float zc[32];
        const float4* zp = (const float4*)zsrc[m];
#pragma unroll
        for (int c = 0; c < 8; ++c) {
            float4 v = zp[c];
            zc[c*4+0] = v.x; zc[c*4+1] = v.y; zc[c*4+2] = v.z; zc[c*4+3] = v.w;
        }
#pragma unroll
        for (int j = 0; j < 32; ++j) {
#pragma unroll
            for (int i = 0; i < 32; ++i)
                acc[j] += zc[i] * W1[j * 128 + m * 32 + i];
        }
    }
    float tv[32];
#pragma unroll
    for (int j = 0; j < 32; ++j) tv[j] = tanhf_(acc[j]);
    float* orow = out + (size_t)node * 32;
#pragma unroll
    for (int ob = 0; ob < 8; ++ob) {
        float o[4];
#pragma unroll
        for (int q = 0; q < 4; ++q) {
            int oj = ob * 4 + q;
            float a = b2[oj];
#pragma unroll
            for (int j = 0; j < 32; ++j)
                a += tv[j] * W2[oj * 32 + j];
            o[q] = a;
        }
        *(float4*)(orow + ob * 4) = make_float4(o[0], o[1], o[2], o[3]);
    }
}

// ---------------------------------------------------------------------------
static inline size_t alignUp(size_t x, size_t a) { return (x + a - 1) & ~(a - 1); }

extern "C" void kernel_launch(void* const* d_in, const int* in_sizes, int n_in,
                              void* d_out, int out_size, void* d_ws, size_t ws_size,
                              hipStream_t stream)
{
    const float* h    = (const float*)d_in[0];
    const int*   idx2 = (const int*)d_in[1];
    const int*   idx3 = (const int*)d_in[2];
    const int*   idx4 = (const int*)d_in[3];
    const float* Wih  = (const float*)d_in[4];
    const float* Whh  = (const float*)d_in[5];
    const float* bih  = (const float*)d_in[6];
    const float* bhh  = (const float*)d_in[7];
    const float* W1   = (const float*)d_in[8];
    const float* b1   = (const float*)d_in[9];
    const float* W2   = (const float*)d_in[10];
    const float* b2   = (const float*)d_in[11];
    float* out = (float*)d_out;

    int n1 = in_sizes[0] / 32;
    int n2 = in_sizes[1] / 2;
    int n3 = in_sizes[2] / 3;
    int n4 = in_sizes[3] / 4;
    int nEmax = n2 > n3 ? n2 : n3; if (n4 > nEmax) nEmax = n4;

    const int NCOL = 6;
    int M = NCOL * n1;
    int B0 = (M + 255) / 256;
    int B1 = (B0 + 255) / 256;
    size_t totE = (size_t)n2 + 2 * (size_t)n3 + 3 * (size_t)n4;

    // ---- workspace layout ----
    size_t off = 0;
    size_t h0Off  = off; off = alignUp(off + (size_t)n1 * 32 * 4, 256);
    size_t hsOff  = off; off = alignUp(off + (size_t)nEmax * 32 * 4, 256);
    size_t hkkOff = off; off = alignUp(off + (size_t)n1 * 32 * 4, 256);
    size_t cntOff = off; off = alignUp(off + (size_t)M * 4, 256);
    size_t c0Off  = off; off = alignUp(off + (size_t)3 * n1 * 4, 256);
    size_t oOff   = off; off = alignUp(off + (size_t)M * 4, 256);
    size_t entOff = off; off = alignUp(off + totE * 4, 256);
    size_t b0Off  = off; off = alignUp(off + (size_t)B0 * 4, 256);
    size_t i1Off  = off; off = alignUp(off + (size_t)B0 * 4, 256);
    size_t b1Off  = off; off = alignUp(off + (size_t)B1 * 4, 256);
    size_t need = off;

    int blocksN1 = (n1 + 255) / 256;
    char* ws = (char*)d_ws;

    if (ws_size >= need && B1 <= 1024) {
        float* h0     = (float*)(ws + h0Off);
        float* hstate = (float*)(ws + hsOff);
        float* hkk    = (float*)(ws + hkkOff);
        int*   counts = (int*)(ws + cntOff);
        int*   cnt0   = (int*)(ws + c0Off);
        int*   offs   = (int*)(ws + oOff);
        int*   ent    = (int*)(ws + entOff);
        int*   bsums0 = (int*)(ws + b0Off);
        int*   incl1  = (int*)(ws + i1Off);
        int*   bsums1 = (int*)(ws + b1Off);

        // --- CSR build ---
        hipMemsetAsync(counts, 0, ((size_t)M + 3 * n1) * 4, stream);
        hist_all<2><<<(n2 * 2 + 255) / 256, 256, 0, stream>>>(idx2, n2 * 2, cnt0,          counts,          n1);
        hist_all<3><<<(n3 * 3 + 255) / 256, 256, 0, stream>>>(idx3, n3 * 3, cnt0 + n1,     counts + n1,     n1);
        hist_all<4><<<(n4 * 4 + 255) / 256, 256, 0, stream>>>(idx4, n4 * 4, cnt0 + 2 * n1, counts + 3 * n1, n1);
        scan_block<<<B0, 256, 0, stream>>>(counts, offs, bsums0, M);
        scan_block<<<B1, 256, 0, stream>>>(bsums0, incl1, bsums1, B0);
        scan_bsums<<<1, 1024, 0, stream>>>(bsums1, B1);
        finalize_joint<<<B0, 256, 0, stream>>>(offs, counts, bsums0, incl1, bsums1, M);
        hipMemcpyAsync(counts, offs, (size_t)M * 4, hipMemcpyDeviceToDevice, stream);
        fill_all<2><<<(n2 * 1 + 255) / 256, 256, 0, stream>>>(idx2, n2 * 1, counts,          ent, n1);
        fill_all<3><<<(n3 * 2 + 255) / 256, 256, 0, stream>>>(idx3, n3 * 2, counts + n1,     ent, n1);
        fill_all<4><<<(n4 * 3 + 255) / 256, 256, 0, stream>>>(idx4, n4 * 3, counts + 3 * n1, ent, n1);

        // --- node-side precomputes ---
        compute_h0<<<blocksN1, 256, 0, stream>>>(h, Wih, bih, bhh, h0, n1);
        init_acc<<<blocksN1, 256, 0, stream>>>(h, W1, b1, out, n1);

        // --- per-k pipeline ---
        const int* idxs[3] = { idx2, idx3, idx4 };
        int nEs[3] = { n2, n3, n4 };
        int colbase[3] = { 0, 1, 3 };
        int gaBlocks = ((n1 * 8) + 255) / 256;

        for (int kk = 0; kk < 3; ++kk) {
            const int* idx = idxs[kk];
            int nE = nEs[kk];

            // size grid: one wave per edge up to 12288 waves (3072 blocks)
            int wavesWanted = (nE < 12288) ? nE : 12288;
            int gwBlocks = (wavesWanted + 3) / 4;
            int totalWaves = gwBlocks * 4;

            init_hkk<<<gaBlocks, 256, 0, stream>>>(cnt0 + kk * n1, h0, hkk, n1);

            int K = kk + 2;
            for (int t = 1; t < K; ++t) {
                if (K == 2)      gru_step_w<2, 1><<<gwBlocks, 256, 0, stream>>>(idx, nE, totalWaves, h, h0, Wih, bih, Whh, bhh, hstate);
                else if (K == 3) {
                    if (t == 1)  gru_step_w<3, 1><<<gwBlocks, 256, 0, stream>>>(idx, nE, totalWaves, h, h0, Wih, bih, Whh, bhh, hstate);
                    else         gru_step_w<3, 2><<<gwBlocks, 256, 0, stream>>>(idx, nE, totalWaves, h, h0, Wih, bih, Whh, bhh, hstate);
                } else {
                    if (t == 1)      gru_step_w<4, 1><<<gwBlocks, 256, 0, stream>>>(idx, nE, totalWaves, h, h0, Wih, bih, Whh, bhh, hstate);
                    else if (t == 2) gru_step_w<4, 2><<<gwBlocks, 256, 0, stream>>>(idx, nE, totalWaves, h, h0, Wih, bih, Whh, bhh, hstate);
                    else             gru_step_w<4, 3><<<gwBlocks, 256, 0, stream>>>(idx, nE, totalWaves, h, h0, Wih, bih, Whh, bhh, hstate);
                }
                int col = colbase[kk] + (t - 1);
                gather_add<<<gaBlocks, 256, 0, stream>>>(
                    offs + (size_t)col * n1, counts + (size_t)col * n1,
                    ent, hstate, hkk, n1);
            }

            fold_w1<<<blocksN1, 256, 0, stream>>>(hkk, W1 + (kk + 1) * 32, out, n1);
        }

        finish_out<<<blocksN1, 256, 0, stream>>>(out, W2, b2, n1);
        return;
    }

    // ===== fallback: atomic path =====
    float* hk = (float*)d_ws;
    hipMemsetAsync(d_ws, 0, (size_t)n1 * 96 * 4, stream);
    gru_edges_atomic_noG<2><<<(n2 + 255) / 256, 256, 0, stream>>>(
        idx2, n2, h, Wih, bih, Whh, bhh, hk);
    gru_edges_atomic_noG<3><<<(n3 + 255) / 256, 256, 0, stream>>>(
        idx3, n3, h, Wih, bih, Whh, bhh, hk + (size_t)n1 * 32);
    gru_edges_atomic_noG<4><<<(n4 + 255) / 256, 256, 0, stream>>>(
        idx4, n4, h, Wih, bih, Whh, bhh, hk + (size_t)n1 * 64);
    mlp_out_fb<<<blocksN1, 256, 0, stream>>>(h, hk, n1, W1, b1, W2, b2, out);
}

// Round 13
// 1675.167 us; speedup vs baseline: 12.5796x; 1.1671x over previous
//
#include <hip/hip_runtime.h>
#include <hip/hip_bf16.h>

__device__ __forceinline__ float sigmoidf_(float x) {
    return 1.0f / (1.0f + __expf(-x));
}
__device__ __forceinline__ float tanhf_(float x) {
    float e = __expf(2.0f * x);
    return 1.0f - 2.0f / (e + 1.0f);
}

#define FMA4(acc, a, b) \
    acc.x = fmaf(a.x, b.x, acc.x); acc.y = fmaf(a.y, b.y, acc.y); \
    acc.z = fmaf(a.z, b.z, acc.z); acc.w = fmaf(a.w, b.w, acc.w);
#define HS(v) (((v).x + (v).y) + ((v).z + (v).w))

// ---------------------------------------------------------------------------
// precompute_G: G[node][0..95] = h[node] @ Wih.T + bih   (Layout-A only)
// ---------------------------------------------------------------------------
__global__ __launch_bounds__(256) void precompute_G(
    const float* __restrict__ h, const float* __restrict__ Wih,
    const float* __restrict__ bih, float* __restrict__ G, int n1)
{
    __shared__ float sW[3072];
    __shared__ float sB[96];
    {
        const float4* a4 = (const float4*)Wih;
        float4* sa = (float4*)sW;
#pragma unroll
        for (int c = 0; c < 3; ++c)
            sa[c * 256 + threadIdx.x] = a4[c * 256 + threadIdx.x];
        if (threadIdx.x < 96) sB[threadIdx.x] = bih[threadIdx.x];
    }
    __syncthreads();

    int node = blockIdx.x * 256 + threadIdx.x;
    if (node >= n1) return;
    float x[32];
    const float4* hx = (const float4*)(h + (size_t)node * 32);
#pragma unroll
    for (int c = 0; c < 8; ++c) {
        float4 v = hx[c];
        x[c*4+0] = v.x; x[c*4+1] = v.y; x[c*4+2] = v.z; x[c*4+3] = v.w;
    }
    float* grow = G + (size_t)node * 96;
#pragma unroll
    for (int jb = 0; jb < 24; ++jb) {
        float o[4];
#pragma unroll
        for (int q = 0; q < 4; ++q) {
            int j = jb * 4 + q;
            float a = sB[j];
            const float4* w4 = (const float4*)(sW + j * 32);
#pragma unroll
            for (int c = 0; c < 8; ++c) {
                float4 w = w4[c];
                a += x[c*4+0]*w.x + x[c*4+1]*w.y + x[c*4+2]*w.z + x[c*4+3]*w.w;
            }
            o[q] = a;
        }
        *(float4*)(grow + jb * 4) = make_float4(o[0], o[1], o[2], o[3]);
    }
}

// ---------------------------------------------------------------------------
// compute_h0_acc: h0[node] = GRU(hprev=0) AND acc(=out) = b1 + h@W1[:,0:32].T
// ---------------------------------------------------------------------------
__global__ __launch_bounds__(256) void compute_h0_acc(
    const float* __restrict__ h, const float* __restrict__ Wih,
    const float* __restrict__ bih, const float* __restrict__ bhh,
    const float* __restrict__ W1, const float* __restrict__ b1,
    float* __restrict__ h0, float* __restrict__ acc, int n1)
{
    __shared__ float sW[3072];
    __shared__ float sB[192];
    __shared__ float sW1[1024];
    __shared__ float sB1[32];
    {
        const float4* a4 = (const float4*)Wih;
        float4* sa = (float4*)sW;
#pragma unroll
        for (int c = 0; c < 3; ++c)
            sa[c * 256 + threadIdx.x] = a4[c * 256 + threadIdx.x];
        if (threadIdx.x < 192)
            sB[threadIdx.x] = (threadIdx.x < 96) ? bih[threadIdx.x]
                                                 : bhh[threadIdx.x - 96];
#pragma unroll
        for (int c = 0; c < 4; ++c) {
            int i = c * 256 + threadIdx.x;
            sW1[i] = W1[(i >> 5) * 128 + (i & 31)];
        }
        if (threadIdx.x < 32) sB1[threadIdx.x] = b1[threadIdx.x];
    }
    __syncthreads();

    int node = blockIdx.x * 256 + threadIdx.x;
    if (node >= n1) return;
    float x[32];
    const float4* hx = (const float4*)(h + (size_t)node * 32);
#pragma unroll
    for (int c = 0; c < 8; ++c) {
        float4 v = hx[c];
        x[c*4+0] = v.x; x[c*4+1] = v.y; x[c*4+2] = v.z; x[c*4+3] = v.w;
    }
    // h0
    float o[32];
#pragma unroll
    for (int j = 0; j < 32; ++j) {
        float ir = sB[j], iz = sB[32 + j], in_ = sB[64 + j];
        const float4* wr = (const float4*)(sW + j * 32);
        const float4* wz = (const float4*)(sW + (32 + j) * 32);
        const float4* wn = (const float4*)(sW + (64 + j) * 32);
#pragma unroll
        for (int c = 0; c < 8; ++c) {
            float4 a = wr[c], b = wz[c], d = wn[c];
            ir  += x[c*4+0]*a.x + x[c*4+1]*a.y + x[c*4+2]*a.z + x[c*4+3]*a.w;
            iz  += x[c*4+0]*b.x + x[c*4+1]*b.y + x[c*4+2]*b.z + x[c*4+3]*b.w;
            in_ += x[c*4+0]*d.x + x[c*4+1]*d.y + x[c*4+2]*d.z + x[c*4+3]*d.w;
        }
        float r = sigmoidf_(ir + sB[96 + j]);
        float z = sigmoidf_(iz + sB[128 + j]);
        float n = tanhf_(in_ + r * sB[160 + j]);
        o[j] = (1.0f - z) * n;
    }
    float4* dst = (float4*)(h0 + (size_t)node * 32);
#pragma unroll
    for (int c = 0; c < 8; ++c)
        dst[c] = make_float4(o[c*4+0], o[c*4+1], o[c*4+2], o[c*4+3]);
    // acc
    float* arow = acc + (size_t)node * 32;
#pragma unroll
    for (int jb = 0; jb < 8; ++jb) {
        float a[4];
#pragma unroll
        for (int q = 0; q < 4; ++q) {
            int j = jb * 4 + q;
            float s = sB1[j];
            const float4* w4 = (const float4*)(sW1 + j * 32);
#pragma unroll
            for (int c = 0; c < 8; ++c) {
                float4 w = w4[c];
                s += x[c*4+0]*w.x + x[c*4+1]*w.y + x[c*4+2]*w.z + x[c*4+3]*w.w;
            }
            a[q] = s;
        }
        *(float4*)(arow + jb * 4) = make_float4(a[0], a[1], a[2], a[3]);
    }
}

// ---------------------------------------------------------------------------
// Batched histogram per k-list
// ---------------------------------------------------------------------------
template <int K>
__global__ __launch_bounds__(256) void hist_all(
    const int* __restrict__ idx, int nI, int* __restrict__ cnt0,
    int* __restrict__ counts, int n1)
{
    int i = blockIdx.x * 256 + threadIdx.x;
    if (i >= nI) return;
    int t = i % K;
    int node = idx[i];
    if (t == 0) atomicAdd(&cnt0[node], 1);
    else        atomicAdd(&counts[(size_t)(t - 1) * n1 + node], 1);
}

// ---------------------------------------------------------------------------
// Scan machinery (3-level)
// ---------------------------------------------------------------------------
__global__ __launch_bounds__(256) void scan_block(
    const int* __restrict__ in, int* __restrict__ incl,
    int* __restrict__ bsums, int n)
{
    __shared__ int s[256];
    int i = blockIdx.x * 256 + threadIdx.x;
    int v = (i < n) ? in[i] : 0;
    s[threadIdx.x] = v;
    __syncthreads();
    for (int d = 1; d < 256; d <<= 1) {
        int tt = (threadIdx.x >= d) ? s[threadIdx.x - d] : 0;
        __syncthreads();
        s[threadIdx.x] += tt;
        __syncthreads();
    }
    if (i < n) incl[i] = s[threadIdx.x];
    if (threadIdx.x == 255) bsums[blockIdx.x] = s[255];
}

__global__ __launch_bounds__(1024) void scan_bsums(int* bsums, int nb)
{
    __shared__ int s[1024];
    int v = (threadIdx.x < nb) ? bsums[threadIdx.x] : 0;
    s[threadIdx.x] = v;
    __syncthreads();
    for (int d = 1; d < 1024; d <<= 1) {
        int tt = (threadIdx.x >= d) ? s[threadIdx.x - d] : 0;
        __syncthreads();
        s[threadIdx.x] += tt;
        __syncthreads();
    }
    if (threadIdx.x < nb) bsums[threadIdx.x] = s[threadIdx.x] - v; // exclusive
}

__global__ __launch_bounds__(256) void finalize_joint(
    int* __restrict__ offs, const int* __restrict__ counts,
    const int* __restrict__ bsums0, const int* __restrict__ incl1,
    const int* __restrict__ bsums1ex, int M)
{
    int i = blockIdx.x * 256 + threadIdx.x;
    if (i >= M) return;
    int b0 = i >> 8, b1 = b0 >> 8;
    offs[i] = offs[i] - counts[i] + (incl1[b0] - bsums0[b0]) + bsums1ex[b1];
}

template <int K>
__global__ __launch_bounds__(256) void fill_all(
    const int* __restrict__ idx, int nW,
    int* __restrict__ cursor, int* __restrict__ ent, int n1)
{
    int i = blockIdx.x * 256 + threadIdx.x;
    if (i >= nW) return;
    int e = i / (K - 1), tt = i % (K - 1);
    int node = idx[(size_t)e * K + tt + 1];
    int p = atomicAdd(&cursor[(size_t)tt * n1 + node], 1);
    ent[p] = e;
}

// ---------------------------------------------------------------------------
// Layout-A GRU step: x-side comes from precomputed G (3 coalesced scalars
// per lane); only Whh lives in registers (48 VGPR). Value-prefetch of next
// edge's G row + indices. One wave per edge.
// ---------------------------------------------------------------------------
template <int K, int T>
__global__ __launch_bounds__(256) void gru_step_g(
    const int* __restrict__ idx, int nE, int totalWaves,
    const float* __restrict__ G, const float* __restrict__ h0,
    const float* __restrict__ Whh, const float* __restrict__ bhh,
    float* __restrict__ hstate)
{
    const int lane = threadIdx.x & 63;
    const int j    = lane & 31;
    const int half = lane >> 5;
    const int wave = (blockIdx.x * 256 + threadIdx.x) >> 6;
    const float4 z4 = make_float4(0.f, 0.f, 0.f, 0.f);

    float4 Uhr[4], Uhz[4], Uhn[4];
    {
        const float* ub = Whh + (size_t)j * 32 + half * 16;
#pragma unroll
        for (int c = 0; c < 4; ++c) {
            Uhr[c] = *(const float4*)(ub + c * 4);
            Uhz[c] = *(const float4*)(ub + 1024 + c * 4);
            Uhn[c] = *(const float4*)(ub + 2048 + c * 4);
        }
    }
    const float bhr = bhh[j], bhz = bhh[32 + j], bhn = bhh[64 + j];

    int e = wave;
    if (e >= nE) return;
    int nodeT_c = idx[(size_t)e * K + T];
    int prev_c  = (T == 1) ? idx[(size_t)e * K] : 0;
    float gr_c, gz_c, gn_c;
    {
        const float* gp = G + (size_t)nodeT_c * 96;
        gr_c = gp[j]; gz_c = gp[32 + j]; gn_c = gp[64 + j];
    }

    for (; e < nE; e += totalWaves) {
        int en = e + totalWaves;
        int nodeT_n = 0, prev_n = 0;
        float gr_n = 0.f, gz_n = 0.f, gn_n = 0.f;
        if (en < nE) {
            nodeT_n = idx[(size_t)en * K + T];
            if (T == 1) prev_n = idx[(size_t)en * K];
            const float* gq = G + (size_t)nodeT_n * 96;
            gr_n = gq[j]; gz_n = gq[32 + j]; gn_n = gq[64 + j];
        }

        float4 HV[4];
        float hvj;
        {
            const float* hp = (T == 1) ? (h0 + (size_t)prev_c * 32)
                                       : (hstate + (size_t)e * 32);
            const float4* p = (const float4*)(hp + half * 16);
#pragma unroll
            for (int c = 0; c < 4; ++c) HV[c] = p[c];
            hvj = hp[j];
        }

        float4 phr = z4, phz = z4, phn = z4;
#pragma unroll
        for (int c = 0; c < 4; ++c) {
            FMA4(phr, HV[c], Uhr[c])
            FMA4(phz, HV[c], Uhz[c])
            FMA4(phn, HV[c], Uhn[c])
        }
        float s_hr = HS(phr);
        float s_hz = HS(phz);
        float s_hn = HS(phn);
        s_hr += __shfl_xor(s_hr, 32);
        s_hz += __shfl_xor(s_hz, 32);
        s_hn += __shfl_xor(s_hn, 32);

        float r = sigmoidf_(gr_c + s_hr + bhr);
        float z = sigmoidf_(gz_c + s_hz + bhz);
        float n = tanhf_(gn_c + r * (s_hn + bhn));
        float ht = (1.0f - z) * n + z * hvj;
        if (half == 0) hstate[(size_t)e * 32 + j] = ht;

        nodeT_c = nodeT_n; prev_c = prev_n;
        gr_c = gr_n; gz_c = gz_n; gn_c = gn_n;
    }
}

// ---------------------------------------------------------------------------
// Layout-B GRU step (R12-proven): full weights in registers, idx prefetch.
// ---------------------------------------------------------------------------
template <int K, int T>
__global__ __launch_bounds__(256) void gru_step_w(
    const int* __restrict__ idx, int nE, int totalWaves,
    const float* __restrict__ h, const float* __restrict__ h0,
    const float* __restrict__ Wih, const float* __restrict__ bih,
    const float* __restrict__ Whh, const float* __restrict__ bhh,
    float* __restrict__ hstate)
{
    const int lane = threadIdx.x & 63;
    const int j    = lane & 31;
    const int half = lane >> 5;
    const int wave = (blockIdx.x * 256 + threadIdx.x) >> 6;
    const float4 z4 = make_float4(0.f, 0.f, 0.f, 0.f);

    float4 Wir[4], Wiz[4], Win[4], Uhr[4], Uhz[4], Uhn[4];
    {
        const float* ib = Wih + (size_t)j * 32 + half * 16;
        const float* ub = Whh + (size_t)j * 32 + half * 16;
#pragma unroll
        for (int c = 0; c < 4; ++c) {
            Wir[c] = *(const float4*)(ib + c * 4);
            Wiz[c] = *(const float4*)(ib + 1024 + c * 4);
            Win[c] = *(const float4*)(ib + 2048 + c * 4);
            Uhr[c] = *(const float4*)(ub + c * 4);
            Uhz[c] = *(const float4*)(ub + 1024 + c * 4);
            Uhn[c] = *(const float4*)(ub + 2048 + c * 4);
        }
    }
    const float bsum_r = bih[j] + bhh[j];
    const float bsum_z = bih[32 + j] + bhh[32 + j];
    const float b_in   = bih[64 + j];
    const float b_hn   = bhh[64 + j];

    int e = wave;
    if (e >= nE) return;
    int nodeT_c = idx[(size_t)e * K + T];
    int prev_c  = (T == 1) ? idx[(size_t)e * K] : 0;

    for (; e < nE; e += totalWaves) {
        int en = e + totalWaves;
        int nodeT_n = 0, prev_n = 0;
        if (en < nE) {
            nodeT_n = idx[(size_t)en * K + T];
            if (T == 1) prev_n = idx[(size_t)en * K];
        }

        float4 HV[4];
        float hvj;
        if (T == 1) {
            const float* hp = h0 + (size_t)prev_c * 32;
            const float4* p = (const float4*)(hp + half * 16);
#pragma unroll
            for (int c = 0; c < 4; ++c) HV[c] = p[c];
            hvj = hp[j];
        } else {
            const float* hp = hstate + (size_t)e * 32;
            const float4* p = (const float4*)(hp + half * 16);
#pragma unroll
            for (int c = 0; c < 4; ++c) HV[c] = p[c];
            hvj = hp[j];
        }
        float4 X[4];
        {
            const float4* p = (const float4*)(h + (size_t)nodeT_c * 32 + half * 16);
#pragma unroll
            for (int c = 0; c < 4; ++c) X[c] = p[c];
        }

        float4 pr = z4, pz = z4, pin = z4, phn = z4;
#pragma unroll
        for (int c = 0; c < 4; ++c) {
            FMA4(pr, X[c], Wir[c])
            FMA4(pr, HV[c], Uhr[c])
            FMA4(pz, X[c], Wiz[c])
            FMA4(pz, HV[c], Uhz[c])
            FMA4(pin, X[c], Win[c])
            FMA4(phn, HV[c], Uhn[c])
        }
        float s_r  = HS(pr);
        float s_z  = HS(pz);
        float s_in = HS(pin);
        float s_hn = HS(phn);
        s_r  += __shfl_xor(s_r, 32);
        s_z  += __shfl_xor(s_z, 32);
        s_in += __shfl_xor(s_in, 32);
        s_hn += __shfl_xor(s_hn, 32);

        float r = sigmoidf_(s_r + bsum_r);
        float z = sigmoidf_(s_z + bsum_z);
        float n = tanhf_((s_in + b_in) + r * (s_hn + b_hn));
        float ht = (1.0f - z) * n + z * hvj;
        if (half == 0) hstate[(size_t)e * 32 + j] = ht;

        nodeT_c = nodeT_n;
        prev_c  = prev_n;
    }
}

// ---------------------------------------------------------------------------
// gather_add<FIRST>: FIRST -> hkk = cnt0*h0 + gather; else hkk += gather.
// 8 threads per node, no atomics.
// ---------------------------------------------------------------------------
template <bool FIRST>
__global__ __launch_bounds__(256) void gather_add(
    const int* __restrict__ offs, const int* __restrict__ endp,
    const int* __restrict__ ent, const float* __restrict__ hstate,
    const int* __restrict__ cnt0, const float* __restrict__ h0,
    float* __restrict__ hkk, int n1)
{
    int gid = blockIdx.x * 256 + threadIdx.x;
    int node = gid >> 3;
    int sub = gid & 7;
    if (node >= n1) return;
    int beg = offs[node], end = endp[node];
    float4 a;
    float* dst = hkk + (size_t)node * 32 + sub * 4;
    if (FIRST) {
        float c = (float)cnt0[node];
        float4 v = *(const float4*)(h0 + (size_t)node * 32 + sub * 4);
        a = make_float4(v.x * c, v.y * c, v.z * c, v.w * c);
    } else {
        if (beg == end) return;
        a = *(float4*)dst;
    }
    for (int p = beg; p < end; ++p) {
        int e = ent[p];
        float4 v = *(const float4*)(hstate + (size_t)e * 32 + sub * 4);
        a.x += v.x; a.y += v.y; a.z += v.z; a.w += v.w;
    }
    *(float4*)dst = a;
}

// ---------------------------------------------------------------------------
// fold_w1<LAST>: acc += hkk@W1blk.T; if LAST also out = tanh(acc)@W2.T + b2
// (acc aliases out).
// ---------------------------------------------------------------------------
template <bool LAST>
__global__ __launch_bounds__(256) void fold_w1(
    const float* __restrict__ hkk, const float* __restrict__ W1blk,
    float* __restrict__ acc, const float* __restrict__ W2,
    const float* __restrict__ b2, int n1)
{
    __shared__ float sW[1024];
    __shared__ float sW2[1024];
#pragma unroll
    for (int c = 0; c < 4; ++c) {
        int i = c * 256 + threadIdx.x;
        sW[i] = W1blk[(i >> 5) * 128 + (i & 31)];
    }
    if (LAST) {
        const float4* w4 = (const float4*)W2;
        float4* s4 = (float4*)sW2;
        s4[threadIdx.x] = w4[threadIdx.x];
    }
    __syncthreads();

    int node = blockIdx.x * 256 + threadIdx.x;
    if (node >= n1) return;
    float x[32];
    const float4* hx = (const float4*)(hkk + (size_t)node * 32);
#pragma unroll
    for (int c = 0; c < 8; ++c) {
        float4 v = hx[c];
        x[c*4+0] = v.x; x[c*4+1] = v.y; x[c*4+2] = v.z; x[c*4+3] = v.w;
    }
    float* arow = acc + (size_t)node * 32;
    float o[32];
#pragma unroll
    for (int jb = 0; jb < 8; ++jb) {
        float4 cur = *(float4*)(arow + jb * 4);
        float t[4] = { cur.x, cur.y, cur.z, cur.w };
#pragma unroll
        for (int q = 0; q < 4; ++q) {
            int j = jb * 4 + q;
            float a = t[q];
            const float4* w4 = (const float4*)(sW + j * 32);
#pragma unroll
            for (int c = 0; c < 8; ++c) {
                float4 w = w4[c];
                a += x[c*4+0]*w.x + x[c*4+1]*w.y + x[c*4+2]*w.z + x[c*4+3]*w.w;
            }
            o[jb*4+q] = a;
        }
    }
    if (!LAST) {
#pragma unroll
        for (int jb = 0; jb < 8; ++jb)
            *(float4*)(arow + jb * 4) =
                make_float4(o[jb*4+0], o[jb*4+1], o[jb*4+2], o[jb*4+3]);
    } else {
        float tv[32];
#pragma unroll
        for (int j = 0; j < 32; ++j) tv[j] = tanhf_(o[j]);
#pragma unroll
        for (int ob = 0; ob < 8; ++ob) {
            float r[4];
#pragma unroll
            for (int q = 0; q < 4; ++q) {
                int oj = ob * 4 + q;
                float a = b2[oj];
                const float4* w4 = (const float4*)(sW2 + oj * 32);
#pragma unroll
                for (int c = 0; c < 8; ++c) {
                    float4 w = w4[c];
                    a += tv[c*4+0]*w.x + tv[c*4+1]*w.y + tv[c*4+2]*w.z + tv[c*4+3]*w.w;
                }
                r[q] = a;
            }
            *(float4*)(arow + ob * 4) = make_float4(r[0], r[1], r[2], r[3]);
        }
    }
}

// ---------------------------------------------------------------------------
// Fallback: atomic scatter (slow, correct)
// ---------------------------------------------------------------------------
template <int K>
__global__ __launch_bounds__(256) void gru_edges_atomic_noG(
    const int* __restrict__ idx, int nE,
    const float* __restrict__ h,
    const float* __restrict__ Wih, const float* __restrict__ bih,
    const float* __restrict__ Whh, const float* __restrict__ bhh,
    float* __restrict__ hk)
{
    int e = blockIdx.x * 256 + threadIdx.x;
    if (e >= nE) return;
    float hv[32];
#pragma unroll
    for (int t = 0; t < K; ++t) {
        int node = idx[(size_t)e * K + t];
        float x[32];
        const float4* hx = (const float4*)(h + (size_t)node * 32);
#pragma unroll
        for (int c = 0; c < 8; ++c) {
            float4 v = hx[c];
            x[c*4+0] = v.x; x[c*4+1] = v.y; x[c*4+2] = v.z; x[c*4+3] = v.w;
        }
        float hn_[32];
#pragma unroll
        for (int j = 0; j < 32; ++j) {
            float ir = bih[j], iz = bih[32 + j], in_ = bih[64 + j];
#pragma unroll
            for (int i = 0; i < 32; ++i) {
                ir  += x[i] * Wih[j * 32 + i];
                iz  += x[i] * Wih[(32 + j) * 32 + i];
                in_ += x[i] * Wih[(64 + j) * 32 + i];
            }
            float hr = bhh[j], hz = bhh[32 + j], hn2 = bhh[64 + j];
            if (t > 0) {
#pragma unroll
                for (int i = 0; i < 32; ++i) {
                    hr  += hv[i] * Whh[j * 32 + i];
                    hz  += hv[i] * Whh[(32 + j) * 32 + i];
                    hn2 += hv[i] * Whh[(64 + j) * 32 + i];
                }
            }
            float r = sigmoidf_(ir + hr);
            float z = sigmoidf_(iz + hz);
            float n = tanhf_(in_ + r * hn2);
            hn_[j] = (t > 0) ? ((1.0f - z) * n + z * hv[j]) : (1.0f - z) * n;
        }
        float* dst = hk + (size_t)node * 32;
#pragma unroll
        for (int j = 0; j < 32; ++j) {
            hv[j] = hn_[j];
            atomicAdd(dst + j, hn_[j]);
        }
    }
}

__global__ __launch_bounds__(256) void mlp_out_fb(
    const float* __restrict__ h, const float* __restrict__ hk, int n1,
    const float* __restrict__ W1, const float* __restrict__ b1,
    const float* __restrict__ W2, const float* __restrict__ b2,
    float* __restrict__ out)
{
    int node = blockIdx.x * 256 + threadIdx.x;
    if (node >= n1) return;
    float acc[32];
#pragma unroll
    for (int j = 0; j < 32; ++j) acc[j] = b1[j];
    const float* zsrc[4];
    zsrc[0] = h + (size_t)node * 32;
    zsrc[1] = hk + (size_t)node * 32;
    zsrc[2] = hk + (size_t)n1 * 32 + (size_t)node * 32;
    zsrc[3] = hk + (size_t)n1 * 64 + (size_t)node * 32;
#pragma unroll
    for (int m = 0; m < 4; ++m) {
        float zc[32];
        const float4* zp = (const float4*)zsrc[m];
#pragma unroll
        for (int c = 0; c < 8; ++c) {
            float4 v = zp[c];
            zc[c*4+0] = v.x; zc[c*4+1] = v.y; zc[c*4+2] = v.z; zc[c*4+3] = v.w;
        }
#pragma unroll
        for (int j = 0; j < 32; ++j) {
#pragma unroll
            for (int i = 0; i < 32; ++i)
                acc[j] += zc[i] * W1[j * 128 + m * 32 + i];
        }
    }
    float tv[32];
#pragma unroll
    for (int j = 0; j < 32; ++j) tv[j] = tanhf_(acc[j]);
    float* orow = out + (size_t)node * 32;
#pragma unroll
    for (int ob = 0; ob < 8; ++ob) {
        float o[4];
#pragma unroll
        for (int q = 0; q < 4; ++q) {
            int oj = ob * 4 + q;
            float a = b2[oj];
#pragma unroll
            for (int j = 0; j < 32; ++j)
                a += tv[j] * W2[oj * 32 + j];
            o[q] = a;
        }
        *(float4*)(orow + ob * 4) = make_float4(o[0], o[1], o[2], o[3]);
    }
}

// ---------------------------------------------------------------------------
static inline size_t alignUp(size_t x, size_t a) { return (x + a - 1) & ~(a - 1); }

extern "C" void kernel_launch(void* const* d_in, const int* in_sizes, int n_in,
                              void* d_out, int out_size, void* d_ws, size_t ws_size,
                              hipStream_t stream)
{
    const float* h    = (const float*)d_in[0];
    const int*   idx2 = (const int*)d_in[1];
    const int*   idx3 = (const int*)d_in[2];
    const int*   idx4 = (const int*)d_in[3];
    const float* Wih  = (const float*)d_in[4];
    const float* Whh  = (const float*)d_in[5];
    const float* bih  = (const float*)d_in[6];
    const float* bhh  = (const float*)d_in[7];
    const float* W1   = (const float*)d_in[8];
    const float* b1   = (const float*)d_in[9];
    const float* W2   = (const float*)d_in[10];
    const float* b2   = (const float*)d_in[11];
    float* out = (float*)d_out;

    int n1 = in_sizes[0] / 32;
    int n2 = in_sizes[1] / 2;
    int n3 = in_sizes[2] / 3;
    int n4 = in_sizes[3] / 4;
    int nEmax = n2 > n3 ? n2 : n3; if (n4 > nEmax) nEmax = n4;

    const int NCOL = 6;
    int M = NCOL * n1;
    int B0 = (M + 255) / 256;
    int B1 = (B0 + 255) / 256;
    size_t totE = (size_t)n2 + 2 * (size_t)n3 + 3 * (size_t)n4;

    // ---- workspace layout ----
    size_t off = 0;
    size_t h0Off  = off; off = alignUp(off + (size_t)n1 * 32 * 4, 256);
    size_t hsOff  = off; off = alignUp(off + (size_t)nEmax * 32 * 4, 256);
    size_t hkkOff = off; off = alignUp(off + (size_t)n1 * 32 * 4, 256);
    size_t cntOff = off; off = alignUp(off + (size_t)M * 4, 256);
    size_t c0Off  = off; off = alignUp(off + (size_t)3 * n1 * 4, 256);
    size_t oOff   = off; off = alignUp(off + (size_t)M * 4, 256);
    size_t entOff = off; off = alignUp(off + totE * 4, 256);
    size_t b0Off  = off; off = alignUp(off + (size_t)B0 * 4, 256);
    size_t i1Off  = off; off = alignUp(off + (size_t)B0 * 4, 256);
    size_t b1Off  = off; off = alignUp(off + (size_t)B1 * 4, 256);
    size_t needB = off;                                   // Layout-B
    size_t gOff   = off; off = alignUp(off + (size_t)n1 * 96 * 4, 256);
    size_t needA = off;                                   // Layout-A (+G)

    int blocksN1 = (n1 + 255) / 256;
    char* ws = (char*)d_ws;

    if (ws_size >= needB && B1 <= 1024) {
        bool useG = (ws_size >= needA);
        float* h0     = (float*)(ws + h0Off);
        float* hstate = (float*)(ws + hsOff);
        float* hkk    = (float*)(ws + hkkOff);
        int*   counts = (int*)(ws + cntOff);
        int*   cnt0   = (int*)(ws + c0Off);
        int*   offs   = (int*)(ws + oOff);
        int*   ent    = (int*)(ws + entOff);
        int*   bsums0 = (int*)(ws + b0Off);
        int*   incl1  = (int*)(ws + i1Off);
        int*   bsums1 = (int*)(ws + b1Off);
        float* G      = useG ? (float*)(ws + gOff) : nullptr;

        // --- CSR build ---
        hipMemsetAsync(counts, 0, ((size_t)M + 3 * n1) * 4, stream);
        hist_all<2><<<(n2 * 2 + 255) / 256, 256, 0, stream>>>(idx2, n2 * 2, cnt0,          counts,          n1);
        hist_all<3><<<(n3 * 3 + 255) / 256, 256, 0, stream>>>(idx3, n3 * 3, cnt0 + n1,     counts + n1,     n1);
        hist_all<4><<<(n4 * 4 + 255) / 256, 256, 0, stream>>>(idx4, n4 * 4, cnt0 + 2 * n1, counts + 3 * n1, n1);
        scan_block<<<B0, 256, 0, stream>>>(counts, offs, bsums0, M);
        scan_block<<<B1, 256, 0, stream>>>(bsums0, incl1, bsums1, B0);
        scan_bsums<<<1, 1024, 0, stream>>>(bsums1, B1);
        finalize_joint<<<B0, 256, 0, stream>>>(offs, counts, bsums0, incl1, bsums1, M);
        hipMemcpyAsync(counts, offs, (size_t)M * 4, hipMemcpyDeviceToDevice, stream);
        fill_all<2><<<(n2 * 1 + 255) / 256, 256, 0, stream>>>(idx2, n2 * 1, counts,          ent, n1);
        fill_all<3><<<(n3 * 2 + 255) / 256, 256, 0, stream>>>(idx3, n3 * 2, counts + n1,     ent, n1);
        fill_all<4><<<(n4 * 3 + 255) / 256, 256, 0, stream>>>(idx4, n4 * 3, counts + 3 * n1, ent, n1);

        // --- node-side precomputes ---
        if (useG)
            precompute_G<<<blocksN1, 256, 0, stream>>>(h, Wih, bih, G, n1);
        compute_h0_acc<<<blocksN1, 256, 0, stream>>>(
            h, Wih, bih, bhh, W1, b1, h0, out, n1);

        // --- per-k pipeline ---
        const int* idxs[3] = { idx2, idx3, idx4 };
        int nEs[3] = { n2, n3, n4 };
        int colbase[3] = { 0, 1, 3 };
        int gaBlocks = ((n1 * 8) + 255) / 256;

        for (int kk = 0; kk < 3; ++kk) {
            const int* idx = idxs[kk];
            int nE = nEs[kk];
            int wavesWanted = (nE < 12288) ? nE : 12288;
            int gwBlocks = (wavesWanted + 3) / 4;
            int totalWaves = gwBlocks * 4;
            int K = kk + 2;

            for (int t = 1; t < K; ++t) {
                if (useG) {
                    if (K == 2)      gru_step_g<2, 1><<<gwBlocks, 256, 0, stream>>>(idx, nE, totalWaves, G, h0, Whh, bhh, hstate);
                    else if (K == 3) {
                        if (t == 1)  gru_step_g<3, 1><<<gwBlocks, 256, 0, stream>>>(idx, nE, totalWaves, G, h0, Whh, bhh, hstate);
                        else         gru_step_g<3, 2><<<gwBlocks, 256, 0, stream>>>(idx, nE, totalWaves, G, h0, Whh, bhh, hstate);
                    } else {
                        if (t == 1)      gru_step_g<4, 1><<<gwBlocks, 256, 0, stream>>>(idx, nE, totalWaves, G, h0, Whh, bhh, hstate);
                        else if (t == 2) gru_step_g<4, 2><<<gwBlocks, 256, 0, stream>>>(idx, nE, totalWaves, G, h0, Whh, bhh, hstate);
                        else             gru_step_g<4, 3><<<gwBlocks, 256, 0, stream>>>(idx, nE, totalWaves, G, h0, Whh, bhh, hstate);
                    }
                } else {
                    if (K == 2)      gru_step_w<2, 1><<<gwBlocks, 256, 0, stream>>>(idx, nE, totalWaves, h, h0, Wih, bih, Whh, bhh, hstate);
                    else if (K == 3) {
                        if (t == 1)  gru_step_w<3, 1><<<gwBlocks, 256, 0, stream>>>(idx, nE, totalWaves, h, h0, Wih, bih, Whh, bhh, hstate);
                        else         gru_step_w<3, 2><<<gwBlocks, 256, 0, stream>>>(idx, nE, totalWaves, h, h0, Wih, bih, Whh, bhh, hstate);
                    } else {
                        if (t == 1)      gru_step_w<4, 1><<<gwBlocks, 256, 0, stream>>>(idx, nE, totalWaves, h, h0, Wih, bih, Whh, bhh, hstate);
                        else if (t == 2) gru_step_w<4, 2><<<gwBlocks, 256, 0, stream>>>(idx, nE, totalWaves, h, h0, Wih, bih, Whh, bhh, hstate);
                        else             gru_step_w<4, 3><<<gwBlocks, 256, 0, stream>>>(idx, nE, totalWaves, h, h0, Wih, bih, Whh, bhh, hstate);
                    }
                }
                int col = colbase[kk] + (t - 1);
                if (t == 1)
                    gather_add<true><<<gaBlocks, 256, 0, stream>>>(
                        offs + (size_t)col * n1, counts + (size_t)col * n1,
                        ent, hstate, cnt0 + kk * n1, h0, hkk, n1);
                else
                    gather_add<false><<<gaBlocks, 256, 0, stream>>>(
                        offs + (size_t)col * n1, counts + (size_t)col * n1,
                        ent, hstate, cnt0 + kk * n1, h0, hkk, n1);
            }

            if (kk < 2)
                fold_w1<false><<<blocksN1, 256, 0, stream>>>(
                    hkk, W1 + (kk + 1) * 32, out, W2, b2, n1);
            else
                fold_w1<true><<<blocksN1, 256, 0, stream>>>(
                    hkk, W1 + (kk + 1) * 32, out, W2, b2, n1);
        }
        return;
    }

    // ===== fallback: atomic path =====
    float* hk = (float*)d_ws;
    hipMemsetAsync(d_ws, 0, (size_t)n1 * 96 * 4, stream);
    gru_edges_atomic_noG<2><<<(n2 + 255) / 256, 256, 0, stream>>>(
        idx2, n2, h, Wih, bih, Whh, bhh, hk);
    gru_edges_atomic_noG<3><<<(n3 + 255) / 256, 256, 0, stream>>>(
        idx3, n3, h, Wih, bih, Whh, bhh, hk + (size_t)n1 * 32);
    gru_edges_atomic_noG<4><<<(n4 + 255) / 256, 256, 0, stream>>>(
        idx4, n4, h, Wih, bih, Whh, bhh, hk + (size_t)n1 * 64);
    mlp_out_fb<<<blocksN1, 256, 0, stream>>>(h, hk, n1, W1, b1, W2, b2, out);
}